// Round 1
// baseline (680.146 us; speedup 1.0000x reference)
//
#include <hip/hip_runtime.h>

#define NNODES 32768
#define NEDGES 524288
#define KCL 64

__device__ __forceinline__ float rl(float v, int lane) {
  return __int_as_float(__builtin_amdgcn_readlane(__float_as_int(v), lane));
}

__device__ __forceinline__ float wave_sum(float v) {
#pragma unroll
  for (int off = 32; off > 0; off >>= 1) v += __shfl_xor(v, off, 64);
  return v;
}

__device__ __forceinline__ float wave_max(float v) {
#pragma unroll
  for (int off = 32; off > 0; off >>= 1) v = fmaxf(v, __shfl_xor(v, off, 64));
  return v;
}

// ---------------- edge preprocessing ----------------
__global__ __launch_bounds__(256) void hist_kernel(const int* __restrict__ src, const int* __restrict__ dst,
                                                   int* __restrict__ indeg, int* __restrict__ outdeg) {
  int e = blockIdx.x * 256 + threadIdx.x;
  atomicAdd(&indeg[dst[e]], 1);
  atomicAdd(&outdeg[src[e]], 1);
}

__global__ __launch_bounds__(1024) void scan_kernel(const int* __restrict__ indeg, int* __restrict__ offs,
                                                    int* __restrict__ cursor, float* __restrict__ dis) {
  __shared__ int part[1024];
  int t = threadIdx.x;
  int base = t * 32;
  int loc[32];
  int s = 0;
#pragma unroll
  for (int i = 0; i < 32; i++) { loc[i] = indeg[base + i]; s += loc[i]; }
  part[t] = s;
  __syncthreads();
  for (int off = 1; off < 1024; off <<= 1) {
    int add = (t >= off) ? part[t - off] : 0;
    __syncthreads();
    part[t] += add;
    __syncthreads();
  }
  int run = (t == 0) ? 0 : part[t - 1];
#pragma unroll
  for (int i = 0; i < 32; i++) {
    offs[base + i] = run;
    cursor[base + i] = run;
    dis[base + i] = rsqrtf((float)loc[i] + 1.0f);
    run += loc[i];
  }
  if (t == 1023) offs[NNODES] = run;
}

__global__ __launch_bounds__(256) void scatter_kernel(const int* __restrict__ src, const int* __restrict__ dst,
                                                      int* __restrict__ cursor, int* __restrict__ ssrc) {
  int e = blockIdx.x * 256 + threadIdx.x;
  int d = dst[e];
  int pos = atomicAdd(&cursor[d], 1);
  ssrc[pos] = src[e];
}

// ---------------- fp32 GEMM: C[M x BN] = A[M x 128] @ W[128 x BN] (+bias, act) ----------------
// ACT: 0 none, 1 relu, 2 tanh. grid.x = M/64, block = 256.
template <int BN, int ACT, int BIAS>
__global__ __launch_bounds__(256) void gemm_kernel(const float* __restrict__ A, const float* __restrict__ W,
                                                   const float* __restrict__ bias, float* __restrict__ C) {
  constexpr int CG = BN / 4;   // column groups of 4
  constexpr int TM = CG / 4;   // rows per thread: 8 (BN=128) or 4 (BN=64)
  __shared__ float As[32][68];  // transposed A tile [k][m], padded row = 272B (16B-aligned)
  __shared__ float Ws[32][BN];
  const int t = threadIdx.x;
  const int tn = t % CG;
  const int tm = t / CG;
  const long rowbase = (long)blockIdx.x * 64;
  float acc[TM][4];
#pragma unroll
  for (int i = 0; i < TM; i++)
#pragma unroll
    for (int j = 0; j < 4; j++) acc[i][j] = 0.f;

  for (int k0 = 0; k0 < 128; k0 += 32) {
#pragma unroll
    for (int it = 0; it < 2; it++) {
      int lin = t + it * 256;
      int row = lin >> 3, c4 = lin & 7;
      float4 v = *reinterpret_cast<const float4*>(A + (rowbase + row) * 128 + k0 + c4 * 4);
      As[c4 * 4 + 0][row] = v.x;
      As[c4 * 4 + 1][row] = v.y;
      As[c4 * 4 + 2][row] = v.z;
      As[c4 * 4 + 3][row] = v.w;
    }
#pragma unroll
    for (int it = 0; it < CG / 8; it++) {
      int lin = t + it * 256;
      int row = lin / CG, c4 = lin % CG;
      *reinterpret_cast<float4*>(&Ws[row][c4 * 4]) =
          *reinterpret_cast<const float4*>(W + (size_t)(k0 + row) * BN + c4 * 4);
    }
    __syncthreads();
#pragma unroll
    for (int k = 0; k < 32; k++) {
      float4 wv = *reinterpret_cast<const float4*>(&Ws[k][tn * 4]);
      float a[TM];
#pragma unroll
      for (int i = 0; i < TM; i += 4) {
        float4 av = *reinterpret_cast<const float4*>(&As[k][tm * TM + i]);
        a[i] = av.x; a[i + 1] = av.y; a[i + 2] = av.z; a[i + 3] = av.w;
      }
#pragma unroll
      for (int i = 0; i < TM; i++) {
        acc[i][0] = fmaf(a[i], wv.x, acc[i][0]);
        acc[i][1] = fmaf(a[i], wv.y, acc[i][1]);
        acc[i][2] = fmaf(a[i], wv.z, acc[i][2]);
        acc[i][3] = fmaf(a[i], wv.w, acc[i][3]);
      }
    }
    __syncthreads();
  }
  float4 bv = {0.f, 0.f, 0.f, 0.f};
  if (BIAS) bv = *reinterpret_cast<const float4*>(bias + tn * 4);
#pragma unroll
  for (int i = 0; i < TM; i++) {
    float r0 = acc[i][0] + bv.x, r1 = acc[i][1] + bv.y;
    float r2 = acc[i][2] + bv.z, r3 = acc[i][3] + bv.w;
    if (ACT == 1) { r0 = fmaxf(r0, 0.f); r1 = fmaxf(r1, 0.f); r2 = fmaxf(r2, 0.f); r3 = fmaxf(r3, 0.f); }
    if (ACT == 2) { r0 = tanhf(r0); r1 = tanhf(r1); r2 = tanhf(r2); r3 = tanhf(r3); }
    float4 out4 = {r0, r1, r2, r3};
    *reinterpret_cast<float4*>(C + (rowbase + tm * TM + i) * BN + tn * 4) = out4;
  }
}

// ---------------- GCN aggregation: out[n] = dis[n]*sum_{src->n} h[src]*dis[src] + h[n]*dis[n]^2 + b ----------------
__global__ __launch_bounds__(256) void aggregate_kernel(const float* __restrict__ hlin, const float* __restrict__ dis,
                                                        const int* __restrict__ offs, const int* __restrict__ ssrc,
                                                        const float* __restrict__ bias, float* __restrict__ outh,
                                                        int relu) {
  const int lane = threadIdx.x & 63;
  const int node = blockIdx.x * 4 + (threadIdx.x >> 6);
  const int e0 = offs[node], e1 = offs[node + 1];
  float ax = 0.f, ay = 0.f;
  for (int e = e0; e < e1; ++e) {
    int s = ssrc[e];
    float w = dis[s];
    float2 hv = *reinterpret_cast<const float2*>(hlin + (size_t)s * 128 + lane * 2);
    ax = fmaf(hv.x, w, ax);
    ay = fmaf(hv.y, w, ay);
  }
  float dn = dis[node];
  float2 hs = *reinterpret_cast<const float2*>(hlin + (size_t)node * 128 + lane * 2);
  float rx = fmaf(ax, dn, hs.x * dn * dn) + bias[lane * 2];
  float ry = fmaf(ay, dn, hs.y * dn * dn) + bias[lane * 2 + 1];
  if (relu) { rx = fmaxf(rx, 0.f); ry = fmaxf(ry, 0.f); }
  float2 r = {rx, ry};
  *reinterpret_cast<float2*>(outh + (size_t)node * 128 + lane * 2) = r;
}

// ---------------- double softmax over K=64 + mincut_den accumulation ----------------
__global__ __launch_bounds__(256) void softmax_kernel(float* __restrict__ s, const int* __restrict__ outdeg,
                                                      float* __restrict__ den) {
  const int wid = threadIdx.x >> 6, lane = threadIdx.x & 63;
  const int node = blockIdx.x * 4 + wid;
  float v = s[(size_t)node * KCL + lane];
  float m = wave_max(v);
  float e = __expf(v - m);
  float s1 = e / wave_sum(e);
  float m2 = wave_max(s1);
  float e2 = __expf(s1 - m2);
  float sd = e2 / wave_sum(e2);
  s[(size_t)node * KCL + lane] = sd;
  float c = wave_sum(sd * sd * (float)outdeg[node]);
  __shared__ float r[4];
  if (lane == 0) r[wid] = c;
  __syncthreads();
  if (threadIdx.x == 0) atomicAdd(&den[node >> 12], r[0] + r[1] + r[2] + r[3]);
}

// ---------------- G[m] = sum_{src->m} s_d[src]  (K=64 gather over dst-CSR) ----------------
__global__ __launch_bounds__(256) void gather_kernel(const float* __restrict__ sd, const int* __restrict__ offs,
                                                     const int* __restrict__ ssrc, float* __restrict__ G) {
  const int lane = threadIdx.x & 63;
  const int node = blockIdx.x * 4 + (threadIdx.x >> 6);
  const int e0 = offs[node], e1 = offs[node + 1];
  float acc = 0.f;
  for (int e = e0; e < e1; ++e) {
    acc += sd[(size_t)ssrc[e] * 64 + lane];
  }
  G[(size_t)node * 64 + lane] = acc;
}

// ---------------- out_adj = G^T s_d ; ss = s_d^T s_d  (per-graph 64x64, atomic merge) ----------------
__global__ __launch_bounds__(256) void atb_kernel(const float* __restrict__ sd, const float* __restrict__ G,
                                                  float* __restrict__ oadj, float* __restrict__ ssb) {
  const int lane = threadIdx.x & 63;
  const int gw = blockIdx.x * 4 + (threadIdx.x >> 6);
  const int n0 = gw * 32;
  const int b = n0 >> 12;
  float accA[64], accS[64];
#pragma unroll
  for (int i = 0; i < 64; i++) { accA[i] = 0.f; accS[i] = 0.f; }
  for (int n = n0; n < n0 + 32; ++n) {
    float sv = sd[(size_t)n * 64 + lane];
    float gv = G[(size_t)n * 64 + lane];
#pragma unroll
    for (int i = 0; i < 64; i++) {
      accA[i] = fmaf(rl(gv, i), sv, accA[i]);
      accS[i] = fmaf(rl(sv, i), sv, accS[i]);
    }
  }
  float* oa = oadj + b * 4096 + lane;
  float* os = ssb + b * 4096 + lane;
#pragma unroll
  for (int i = 0; i < 64; i++) {
    atomicAdd(oa + i * 64, accA[i]);
    atomicAdd(os + i * 64, accS[i]);
  }
}

// ---------------- out_pool = s_d^T h2  (per-graph 64x128, atomic merge) ----------------
__global__ __launch_bounds__(256) void pool_kernel(const float* __restrict__ sd, const float* __restrict__ h2,
                                                   float* __restrict__ outp) {
  const int lane = threadIdx.x & 63;
  const int gw = blockIdx.x * 4 + (threadIdx.x >> 6);
  const int n0 = gw * 32;
  const int b = n0 >> 12;
  float ax[64], ay[64];
#pragma unroll
  for (int i = 0; i < 64; i++) { ax[i] = 0.f; ay[i] = 0.f; }
  for (int n = n0; n < n0 + 32; ++n) {
    float sv = sd[(size_t)n * 64 + lane];
    float2 hv = *reinterpret_cast<const float2*>(h2 + (size_t)n * 128 + lane * 2);
#pragma unroll
    for (int i = 0; i < 64; i++) {
      float si = rl(sv, i);
      ax[i] = fmaf(si, hv.x, ax[i]);
      ay[i] = fmaf(si, hv.y, ay[i]);
    }
  }
  float* op = outp + b * 8192 + lane * 2;
#pragma unroll
  for (int i = 0; i < 64; i++) {
    atomicAdd(op + i * 128, ax[i]);
    atomicAdd(op + i * 128 + 1, ay[i]);
  }
}

// ---------------- losses + adjacency normalization + pooled_batch ----------------
__global__ __launch_bounds__(256) void epilogue_kernel(const float* __restrict__ oadj, const float* __restrict__ ssb,
                                                       const float* __restrict__ den, float* __restrict__ out) {
  const int b = blockIdx.x, t = threadIdx.x;
  const float* A = oadj + b * 4096;
  const float* S = ssb + b * 4096;
  const int row = t >> 2, p = t & 3;
  float rs = 0.f, tra = 0.f, trs = 0.f, ssq = 0.f;
#pragma unroll
  for (int c = 0; c < 16; c++) {
    int j = p * 16 + c;
    float v = A[row * 64 + j];
    float w = S[row * 64 + j];
    ssq += w * w;
    if (j == row) { tra += v; trs += w; }
    else rs += v;
  }
  __shared__ float red[256];
  __shared__ float rowsum[64];
  red[t] = rs;
  __syncthreads();
  if (p == 0) rowsum[row] = red[t] + red[t + 1] + red[t + 2] + red[t + 3];
  float v1 = wave_sum(tra), v2 = wave_sum(trs), v3 = wave_sum(ssq);
  __shared__ float w1[4], w2[4], w3[4];
  if ((t & 63) == 0) { int w = t >> 6; w1[w] = v1; w2[w] = v2; w3[w] = v3; }
  __syncthreads();
  if (t == 0) {
    float TRA = w1[0] + w1[1] + w1[2] + w1[3];
    float TRS = w2[0] + w2[1] + w2[2] + w2[3];
    float SSQ = w3[0] + w3[1] + w3[2] + w3[3];
    atomicAdd(&out[98816], -(TRA / den[b]) * 0.125f);
    // ||ss/||ss|| - I/8||_F^2 = 2 - tr(ss)/(4*||ss||)
    float ssn = sqrtf(SSQ);
    atomicAdd(&out[98817], sqrtf(2.0f - TRS / (4.0f * ssn)) * 0.125f);
  }
  float di = sqrtf(rowsum[row]) + 1e-15f;
#pragma unroll
  for (int c = 0; c < 16; c++) {
    int j = p * 16 + c;
    float v = (j == row) ? 0.f : A[row * 64 + j];
    float dj = sqrtf(rowsum[j]) + 1e-15f;
    out[65536 + b * 4096 + row * 64 + j] = v / (di * dj);
  }
  if (t < 64) out[98304 + b * 64 + t] = (float)b;
}

extern "C" void kernel_launch(void* const* d_in, const int* in_sizes, int n_in,
                              void* d_out, int out_size, void* d_ws, size_t ws_size,
                              hipStream_t stream) {
  const float* x   = (const float*)d_in[0];
  const int*   ei  = (const int*)d_in[1];
  const float* W1  = (const float*)d_in[3];
  const float* b1  = (const float*)d_in[4];
  const float* W2  = (const float*)d_in[5];
  const float* b2  = (const float*)d_in[6];
  const float* Wa1 = (const float*)d_in[7];
  const float* ba1 = (const float*)d_in[8];
  const float* Wa2 = (const float*)d_in[9];
  const float* ba2 = (const float*)d_in[10];
  const float* Wo  = (const float*)d_in[11];
  const float* bo  = (const float*)d_in[12];
  const int* src = ei;
  const int* dst = ei + NEDGES;
  float* out = (float*)d_out;

  char* ws = (char*)d_ws;
  size_t o = 0;
  auto alloc = [&](size_t bytes) -> void* {
    void* p = ws + o;
    o += (bytes + 255) & ~(size_t)255;
    return p;
  };
  float* bufA  = (float*)alloc((size_t)NNODES * 128 * 4);  // 16 MB
  float* bufB  = (float*)alloc((size_t)NNODES * 128 * 4);  // 16 MB
  float* sbuf  = (float*)alloc((size_t)NNODES * 64 * 4);   // 8 MB (logits -> s_d in place)
  float* Gbuf  = (float*)alloc((size_t)NNODES * 64 * 4);   // 8 MB
  float* dis   = (float*)alloc((size_t)NNODES * 4);
  int* indeg   = (int*)alloc((size_t)NNODES * 4);
  int* outdeg  = (int*)alloc((size_t)NNODES * 4);
  int* offs    = (int*)alloc((size_t)(NNODES + 1) * 4);
  int* cursor  = (int*)alloc((size_t)NNODES * 4);
  int* ssrc    = (int*)alloc((size_t)NEDGES * 4);          // 2 MB
  float* oadj  = (float*)alloc(8 * 4096 * 4);
  float* ssb   = (float*)alloc(8 * 4096 * 4);
  float* outp  = (float*)alloc(8 * 8192 * 4);
  float* den   = (float*)alloc(8 * 4);

  hipMemsetAsync(d_out, 0, (size_t)out_size * 4, stream);
  hipMemsetAsync(indeg, 0, (size_t)NNODES * 4, stream);
  hipMemsetAsync(outdeg, 0, (size_t)NNODES * 4, stream);
  hipMemsetAsync(oadj, 0, 8 * 4096 * 4, stream);
  hipMemsetAsync(ssb, 0, 8 * 4096 * 4, stream);
  hipMemsetAsync(outp, 0, 8 * 8192 * 4, stream);
  hipMemsetAsync(den, 0, 8 * 4, stream);

  hist_kernel<<<NEDGES / 256, 256, 0, stream>>>(src, dst, indeg, outdeg);
  scan_kernel<<<1, 1024, 0, stream>>>(indeg, offs, cursor, dis);
  scatter_kernel<<<NEDGES / 256, 256, 0, stream>>>(src, dst, cursor, ssrc);

  // GCN layer 1: h1 = relu(agg(x @ W1) + b1)
  gemm_kernel<128, 0, 0><<<NNODES / 64, 256, 0, stream>>>(x, W1, nullptr, bufA);
  aggregate_kernel<<<NNODES / 4, 256, 0, stream>>>(bufA, dis, offs, ssrc, b1, bufB, 1);
  // GCN layer 2: h2 = agg(h1 @ W2) + b2
  gemm_kernel<128, 0, 0><<<NNODES / 64, 256, 0, stream>>>(bufB, W2, nullptr, bufA);
  aggregate_kernel<<<NNODES / 4, 256, 0, stream>>>(bufA, dis, offs, ssrc, b2, bufB, 0);
  // wait: aggregate #2 must not overwrite its own input; input bufA, output -> bufB is safe
  // (bufB held h1, dead after the W2 GEMM).

  // assignment MLP: z = tanh(h2 @ Wa1 + ba1); logits = z @ Wa2 + ba2
  gemm_kernel<128, 2, 1><<<NNODES / 64, 256, 0, stream>>>(bufB, Wa1, ba1, bufA);
  gemm_kernel<64, 0, 1><<<NNODES / 64, 256, 0, stream>>>(bufA, Wa2, ba2, sbuf);
  // double softmax + mincut_den
  softmax_kernel<<<NNODES / 4, 256, 0, stream>>>(sbuf, outdeg, den);
  // G = A_row-gather of s_d ; then out_adj = G^T s_d, ss = s_d^T s_d, out_pool = s_d^T h2
  gather_kernel<<<NNODES / 4, 256, 0, stream>>>(sbuf, offs, ssrc, Gbuf);
  atb_kernel<<<256, 256, 0, stream>>>(sbuf, Gbuf, oadj, ssb);
  pool_kernel<<<256, 256, 0, stream>>>(sbuf, bufB, outp);
  // pooled_x = relu(out_pool @ Wo + bo) -> out[0:65536]
  gemm_kernel<128, 1, 1><<<512 / 64, 256, 0, stream>>>(outp, Wo, bo, out);
  // losses, normalized out_adj, pooled_batch
  epilogue_kernel<<<8, 256, 0, stream>>>(oadj, ssb, den, out);
}

// Round 2
// 653.007 us; speedup vs baseline: 1.0416x; 1.0416x over previous
//
#include <hip/hip_runtime.h>

#define NNODES 32768
#define NEDGES 524288
#define KCL 64
#define PB 16  // partial blocks per graph for the rank reductions

__device__ __forceinline__ float rl(float v, int lane) {
  return __int_as_float(__builtin_amdgcn_readlane(__float_as_int(v), lane));
}

__device__ __forceinline__ float wave_sum(float v) {
#pragma unroll
  for (int off = 32; off > 0; off >>= 1) v += __shfl_xor(v, off, 64);
  return v;
}

__device__ __forceinline__ float wave_max(float v) {
#pragma unroll
  for (int off = 32; off > 0; off >>= 1) v = fmaxf(v, __shfl_xor(v, off, 64));
  return v;
}

// ---------------- edge preprocessing ----------------
__global__ __launch_bounds__(256) void hist_kernel(const int* __restrict__ src, const int* __restrict__ dst,
                                                   int* __restrict__ indeg, int* __restrict__ outdeg) {
  int e = blockIdx.x * 256 + threadIdx.x;
  atomicAdd(&indeg[dst[e]], 1);
  atomicAdd(&outdeg[src[e]], 1);
}

__global__ __launch_bounds__(1024) void scan_kernel(const int* __restrict__ indeg, int* __restrict__ offs,
                                                    int* __restrict__ cursor, float* __restrict__ dis) {
  __shared__ int part[1024];
  int t = threadIdx.x;
  int base = t * 32;
  int loc[32];
  int s = 0;
#pragma unroll
  for (int i = 0; i < 32; i++) { loc[i] = indeg[base + i]; s += loc[i]; }
  part[t] = s;
  __syncthreads();
  for (int off = 1; off < 1024; off <<= 1) {
    int add = (t >= off) ? part[t - off] : 0;
    __syncthreads();
    part[t] += add;
    __syncthreads();
  }
  int run = (t == 0) ? 0 : part[t - 1];
#pragma unroll
  for (int i = 0; i < 32; i++) {
    offs[base + i] = run;
    cursor[base + i] = run;
    dis[base + i] = rsqrtf((float)loc[i] + 1.0f);
    run += loc[i];
  }
  if (t == 1023) offs[NNODES] = run;
}

__global__ __launch_bounds__(256) void scatter_kernel(const int* __restrict__ src, const int* __restrict__ dst,
                                                      int* __restrict__ cursor, int* __restrict__ ssrc) {
  int e = blockIdx.x * 256 + threadIdx.x;
  int d = dst[e];
  int pos = atomicAdd(&cursor[d], 1);
  ssrc[pos] = src[e];
}

// ---------------- fp32 GEMM: C[M x BN] = A[M x 128] @ W[128 x BN] (+bias, act) ----------------
template <int BN, int ACT, int BIAS>
__global__ __launch_bounds__(256) void gemm_kernel(const float* __restrict__ A, const float* __restrict__ W,
                                                   const float* __restrict__ bias, float* __restrict__ C) {
  constexpr int CG = BN / 4;
  constexpr int TM = CG / 4;
  __shared__ float As[32][68];
  __shared__ float Ws[32][BN];
  const int t = threadIdx.x;
  const int tn = t % CG;
  const int tm = t / CG;
  const long rowbase = (long)blockIdx.x * 64;
  float acc[TM][4];
#pragma unroll
  for (int i = 0; i < TM; i++)
#pragma unroll
    for (int j = 0; j < 4; j++) acc[i][j] = 0.f;

  for (int k0 = 0; k0 < 128; k0 += 32) {
#pragma unroll
    for (int it = 0; it < 2; it++) {
      int lin = t + it * 256;
      int row = lin >> 3, c4 = lin & 7;
      float4 v = *reinterpret_cast<const float4*>(A + (rowbase + row) * 128 + k0 + c4 * 4);
      As[c4 * 4 + 0][row] = v.x;
      As[c4 * 4 + 1][row] = v.y;
      As[c4 * 4 + 2][row] = v.z;
      As[c4 * 4 + 3][row] = v.w;
    }
#pragma unroll
    for (int it = 0; it < CG / 8; it++) {
      int lin = t + it * 256;
      int row = lin / CG, c4 = lin % CG;
      *reinterpret_cast<float4*>(&Ws[row][c4 * 4]) =
          *reinterpret_cast<const float4*>(W + (size_t)(k0 + row) * BN + c4 * 4);
    }
    __syncthreads();
#pragma unroll
    for (int k = 0; k < 32; k++) {
      float4 wv = *reinterpret_cast<const float4*>(&Ws[k][tn * 4]);
      float a[TM];
#pragma unroll
      for (int i = 0; i < TM; i += 4) {
        float4 av = *reinterpret_cast<const float4*>(&As[k][tm * TM + i]);
        a[i] = av.x; a[i + 1] = av.y; a[i + 2] = av.z; a[i + 3] = av.w;
      }
#pragma unroll
      for (int i = 0; i < TM; i++) {
        acc[i][0] = fmaf(a[i], wv.x, acc[i][0]);
        acc[i][1] = fmaf(a[i], wv.y, acc[i][1]);
        acc[i][2] = fmaf(a[i], wv.z, acc[i][2]);
        acc[i][3] = fmaf(a[i], wv.w, acc[i][3]);
      }
    }
    __syncthreads();
  }
  float4 bv = {0.f, 0.f, 0.f, 0.f};
  if (BIAS) bv = *reinterpret_cast<const float4*>(bias + tn * 4);
#pragma unroll
  for (int i = 0; i < TM; i++) {
    float r0 = acc[i][0] + bv.x, r1 = acc[i][1] + bv.y;
    float r2 = acc[i][2] + bv.z, r3 = acc[i][3] + bv.w;
    if (ACT == 1) { r0 = fmaxf(r0, 0.f); r1 = fmaxf(r1, 0.f); r2 = fmaxf(r2, 0.f); r3 = fmaxf(r3, 0.f); }
    if (ACT == 2) { r0 = tanhf(r0); r1 = tanhf(r1); r2 = tanhf(r2); r3 = tanhf(r3); }
    float4 out4 = {r0, r1, r2, r3};
    *reinterpret_cast<float4*>(C + (rowbase + tm * TM + i) * BN + tn * 4) = out4;
  }
}

// ---------------- GCN aggregation ----------------
__global__ __launch_bounds__(256) void aggregate_kernel(const float* __restrict__ hlin, const float* __restrict__ dis,
                                                        const int* __restrict__ offs, const int* __restrict__ ssrc,
                                                        const float* __restrict__ bias, float* __restrict__ outh,
                                                        int relu) {
  const int lane = threadIdx.x & 63;
  const int node = blockIdx.x * 4 + (threadIdx.x >> 6);
  const int e0 = offs[node], e1 = offs[node + 1];
  float ax = 0.f, ay = 0.f;
  for (int e = e0; e < e1; ++e) {
    int s = ssrc[e];
    float w = dis[s];
    float2 hv = *reinterpret_cast<const float2*>(hlin + (size_t)s * 128 + lane * 2);
    ax = fmaf(hv.x, w, ax);
    ay = fmaf(hv.y, w, ay);
  }
  float dn = dis[node];
  float2 hs = *reinterpret_cast<const float2*>(hlin + (size_t)node * 128 + lane * 2);
  float rx = fmaf(ax, dn, hs.x * dn * dn) + bias[lane * 2];
  float ry = fmaf(ay, dn, hs.y * dn * dn) + bias[lane * 2 + 1];
  if (relu) { rx = fmaxf(rx, 0.f); ry = fmaxf(ry, 0.f); }
  float2 r = {rx, ry};
  *reinterpret_cast<float2*>(outh + (size_t)node * 128 + lane * 2) = r;
}

// ---------------- double softmax over K=64 (no atomics) ----------------
__global__ __launch_bounds__(256) void softmax_kernel(float* __restrict__ s) {
  const int lane = threadIdx.x & 63;
  const int node = blockIdx.x * 4 + (threadIdx.x >> 6);
  float v = s[(size_t)node * KCL + lane];
  float m = wave_max(v);
  float e = __expf(v - m);
  float s1 = e / wave_sum(e);
  float m2 = wave_max(s1);
  float e2 = __expf(s1 - m2);
  float sd = e2 / wave_sum(e2);
  s[(size_t)node * KCL + lane] = sd;
}

// ---------------- G[m] = sum_{src->m} s_d[src] ----------------
__global__ __launch_bounds__(256) void gather_kernel(const float* __restrict__ sd, const int* __restrict__ offs,
                                                     const int* __restrict__ ssrc, float* __restrict__ G) {
  const int lane = threadIdx.x & 63;
  const int node = blockIdx.x * 4 + (threadIdx.x >> 6);
  const int e0 = offs[node], e1 = offs[node + 1];
  float acc = 0.f;
  for (int e = e0; e < e1; ++e) {
    acc += sd[(size_t)ssrc[e] * 64 + lane];
  }
  G[(size_t)node * 64 + lane] = acc;
}

// ---------------- out_adj partials: pA[bx] = G_chunk^T s_chunk  (no global atomics) ----------------
__global__ __launch_bounds__(512) void atbA_kernel(const float* __restrict__ sd, const float* __restrict__ G,
                                                   float* __restrict__ pA) {
  __shared__ float lA[4096];
  const int t = threadIdx.x;
  const int lane = t & 63, w = t >> 6;
  const int g = blockIdx.x >> 4, chunk = blockIdx.x & 15;
  const int n0 = g * 4096 + chunk * 256 + w * 32;
#pragma unroll
  for (int i = 0; i < 8; i++) lA[t + i * 512] = 0.f;
  float acc[64];
#pragma unroll
  for (int i = 0; i < 64; i++) acc[i] = 0.f;
  for (int n = n0; n < n0 + 32; ++n) {
    float sv = sd[(size_t)n * 64 + lane];
    float gv = G[(size_t)n * 64 + lane];
#pragma unroll
    for (int i = 0; i < 64; i++) acc[i] = fmaf(rl(gv, i), sv, acc[i]);
  }
  __syncthreads();
#pragma unroll
  for (int i = 0; i < 64; i++) atomicAdd(&lA[i * 64 + lane], acc[i]);
  __syncthreads();
  float* dst = pA + (size_t)blockIdx.x * 4096;
#pragma unroll
  for (int i = 0; i < 8; i++) dst[t + i * 512] = lA[t + i * 512];
}

// ---------------- ss partials + mincut_den partials ----------------
__global__ __launch_bounds__(512) void atbS_kernel(const float* __restrict__ sd, const int* __restrict__ outdeg,
                                                   float* __restrict__ pS, float* __restrict__ denp) {
  __shared__ float lS[4096];
  __shared__ float wden[8];
  const int t = threadIdx.x;
  const int lane = t & 63, w = t >> 6;
  const int g = blockIdx.x >> 4, chunk = blockIdx.x & 15;
  const int n0 = g * 4096 + chunk * 256 + w * 32;
#pragma unroll
  for (int i = 0; i < 8; i++) lS[t + i * 512] = 0.f;
  float acc[64];
#pragma unroll
  for (int i = 0; i < 64; i++) acc[i] = 0.f;
  float dacc = 0.f;
  for (int n = n0; n < n0 + 32; ++n) {
    float sv = sd[(size_t)n * 64 + lane];
    float dg = (float)outdeg[n];
    dacc = fmaf(sv * sv, dg, dacc);
#pragma unroll
    for (int i = 0; i < 64; i++) acc[i] = fmaf(rl(sv, i), sv, acc[i]);
  }
  float dsum = wave_sum(dacc);
  if (lane == 0) wden[w] = dsum;
  __syncthreads();
#pragma unroll
  for (int i = 0; i < 64; i++) atomicAdd(&lS[i * 64 + lane], acc[i]);
  __syncthreads();
  float* dst = pS + (size_t)blockIdx.x * 4096;
#pragma unroll
  for (int i = 0; i < 8; i++) dst[t + i * 512] = lS[t + i * 512];
  if (t == 0) {
    float d = 0.f;
#pragma unroll
    for (int i = 0; i < 8; i++) d += wden[i];
    denp[blockIdx.x] = d;
  }
}

// ---------------- pooled-x partials: pP[bx] = s_chunk^T h2_chunk ----------------
__global__ __launch_bounds__(512) void pool_kernel(const float* __restrict__ sd, const float* __restrict__ h2,
                                                   float* __restrict__ pP) {
  __shared__ float lP[8192];
  const int t = threadIdx.x;
  const int lane = t & 63, w = t >> 6;
  const int g = blockIdx.x >> 4, chunk = blockIdx.x & 15;
  const int n0 = g * 4096 + chunk * 256 + w * 32;
#pragma unroll
  for (int i = 0; i < 16; i++) lP[t + i * 512] = 0.f;
  float ax[64], ay[64];
#pragma unroll
  for (int i = 0; i < 64; i++) { ax[i] = 0.f; ay[i] = 0.f; }
  for (int n = n0; n < n0 + 32; ++n) {
    float sv = sd[(size_t)n * 64 + lane];
    float hx = h2[(size_t)n * 128 + lane];        // col = lane
    float hy = h2[(size_t)n * 128 + 64 + lane];   // col = lane + 64
#pragma unroll
    for (int i = 0; i < 64; i++) {
      float si = rl(sv, i);
      ax[i] = fmaf(si, hx, ax[i]);
      ay[i] = fmaf(si, hy, ay[i]);
    }
  }
  __syncthreads();
#pragma unroll
  for (int i = 0; i < 64; i++) {
    atomicAdd(&lP[i * 128 + lane], ax[i]);
    atomicAdd(&lP[i * 128 + 64 + lane], ay[i]);
  }
  __syncthreads();
  float* dst = pP + (size_t)blockIdx.x * 8192;
#pragma unroll
  for (int i = 0; i < 16; i++) dst[t + i * 512] = lP[t + i * 512];
}

// ---------------- merge partials: 16 per graph ----------------
__global__ __launch_bounds__(512) void merge_kernel(const float* __restrict__ pA, const float* __restrict__ pS,
                                                    const float* __restrict__ pP, float* __restrict__ oadj,
                                                    float* __restrict__ ssb, float* __restrict__ outp) {
  int idx = blockIdx.x * 512 + threadIdx.x;
  if (idx < 32768) {
    int g = idx >> 12, off = idx & 4095;
    float s = 0.f;
#pragma unroll
    for (int q = 0; q < PB; q++) s += pA[(size_t)(g * PB + q) * 4096 + off];
    oadj[idx] = s;
  } else if (idx < 65536) {
    int j = idx - 32768;
    int g = j >> 12, off = j & 4095;
    float s = 0.f;
#pragma unroll
    for (int q = 0; q < PB; q++) s += pS[(size_t)(g * PB + q) * 4096 + off];
    ssb[j] = s;
  } else {
    int j = idx - 65536;
    int g = j >> 13, off = j & 8191;
    float s = 0.f;
#pragma unroll
    for (int q = 0; q < PB; q++) s += pP[(size_t)(g * PB + q) * 8192 + off];
    outp[j] = s;
  }
}

// ---------------- losses + adjacency normalization + pooled_batch ----------------
__global__ __launch_bounds__(256) void epilogue_kernel(const float* __restrict__ oadj, const float* __restrict__ ssb,
                                                       const float* __restrict__ denp, float* __restrict__ out) {
  const int b = blockIdx.x, t = threadIdx.x;
  const float* A = oadj + b * 4096;
  const float* S = ssb + b * 4096;
  const int row = t >> 2, p = t & 3;
  float rs = 0.f, tra = 0.f, trs = 0.f, ssq = 0.f;
#pragma unroll
  for (int c = 0; c < 16; c++) {
    int j = p * 16 + c;
    float v = A[row * 64 + j];
    float w = S[row * 64 + j];
    ssq += w * w;
    if (j == row) { tra += v; trs += w; }
    else rs += v;
  }
  __shared__ float red[256];
  __shared__ float rowsum[64];
  red[t] = rs;
  __syncthreads();
  if (p == 0) rowsum[row] = red[t] + red[t + 1] + red[t + 2] + red[t + 3];
  float v1 = wave_sum(tra), v2 = wave_sum(trs), v3 = wave_sum(ssq);
  __shared__ float w1[4], w2[4], w3[4];
  if ((t & 63) == 0) { int w = t >> 6; w1[w] = v1; w2[w] = v2; w3[w] = v3; }
  __syncthreads();
  if (t == 0) {
    float TRA = w1[0] + w1[1] + w1[2] + w1[3];
    float TRS = w2[0] + w2[1] + w2[2] + w2[3];
    float SSQ = w3[0] + w3[1] + w3[2] + w3[3];
    float db = 0.f;
#pragma unroll
    for (int q = 0; q < PB; q++) db += denp[b * PB + q];
    atomicAdd(&out[98816], -(TRA / db) * 0.125f);
    float ssn = sqrtf(SSQ);
    atomicAdd(&out[98817], sqrtf(2.0f - TRS / (4.0f * ssn)) * 0.125f);
  }
  float di = sqrtf(rowsum[row]) + 1e-15f;
#pragma unroll
  for (int c = 0; c < 16; c++) {
    int j = p * 16 + c;
    float v = (j == row) ? 0.f : A[row * 64 + j];
    float dj = sqrtf(rowsum[j]) + 1e-15f;
    out[65536 + b * 4096 + row * 64 + j] = v / (di * dj);
  }
  if (t < 64) out[98304 + b * 64 + t] = (float)b;
}

extern "C" void kernel_launch(void* const* d_in, const int* in_sizes, int n_in,
                              void* d_out, int out_size, void* d_ws, size_t ws_size,
                              hipStream_t stream) {
  const float* x   = (const float*)d_in[0];
  const int*   ei  = (const int*)d_in[1];
  const float* W1  = (const float*)d_in[3];
  const float* b1  = (const float*)d_in[4];
  const float* W2  = (const float*)d_in[5];
  const float* b2  = (const float*)d_in[6];
  const float* Wa1 = (const float*)d_in[7];
  const float* ba1 = (const float*)d_in[8];
  const float* Wa2 = (const float*)d_in[9];
  const float* ba2 = (const float*)d_in[10];
  const float* Wo  = (const float*)d_in[11];
  const float* bo  = (const float*)d_in[12];
  const int* src = ei;
  const int* dst = ei + NEDGES;
  float* out = (float*)d_out;

  char* ws = (char*)d_ws;
  size_t o = 0;
  auto alloc = [&](size_t bytes) -> void* {
    void* p = ws + o;
    o += (bytes + 255) & ~(size_t)255;
    return p;
  };
  float* bufA  = (float*)alloc((size_t)NNODES * 128 * 4);
  float* bufB  = (float*)alloc((size_t)NNODES * 128 * 4);
  float* sbuf  = (float*)alloc((size_t)NNODES * 64 * 4);
  float* Gbuf  = (float*)alloc((size_t)NNODES * 64 * 4);
  float* dis   = (float*)alloc((size_t)NNODES * 4);
  int* indeg   = (int*)alloc((size_t)NNODES * 4);
  int* outdeg  = (int*)alloc((size_t)NNODES * 4);
  int* offs    = (int*)alloc((size_t)(NNODES + 1) * 4);
  int* cursor  = (int*)alloc((size_t)NNODES * 4);
  int* ssrc    = (int*)alloc((size_t)NEDGES * 4);
  float* pA    = (float*)alloc((size_t)8 * PB * 4096 * 4);  // 2 MB
  float* pS    = (float*)alloc((size_t)8 * PB * 4096 * 4);  // 2 MB
  float* pP    = (float*)alloc((size_t)8 * PB * 8192 * 4);  // 4 MB
  float* denp  = (float*)alloc((size_t)8 * PB * 4);
  float* oadj  = (float*)alloc(8 * 4096 * 4);
  float* ssb   = (float*)alloc(8 * 4096 * 4);
  float* outp  = (float*)alloc(8 * 8192 * 4);

  hipMemsetAsync(d_out, 0, (size_t)out_size * 4, stream);
  hipMemsetAsync(indeg, 0, (size_t)NNODES * 4, stream);
  hipMemsetAsync(outdeg, 0, (size_t)NNODES * 4, stream);

  hist_kernel<<<NEDGES / 256, 256, 0, stream>>>(src, dst, indeg, outdeg);
  scan_kernel<<<1, 1024, 0, stream>>>(indeg, offs, cursor, dis);
  scatter_kernel<<<NEDGES / 256, 256, 0, stream>>>(src, dst, cursor, ssrc);

  // GCN layer 1: h1 = relu(agg(x @ W1) + b1)
  gemm_kernel<128, 0, 0><<<NNODES / 64, 256, 0, stream>>>(x, W1, nullptr, bufA);
  aggregate_kernel<<<NNODES / 4, 256, 0, stream>>>(bufA, dis, offs, ssrc, b1, bufB, 1);
  // GCN layer 2: h2 = agg(h1 @ W2) + b2
  gemm_kernel<128, 0, 0><<<NNODES / 64, 256, 0, stream>>>(bufB, W2, nullptr, bufA);
  aggregate_kernel<<<NNODES / 4, 256, 0, stream>>>(bufA, dis, offs, ssrc, b2, bufB, 0);

  // assignment MLP: z = tanh(h2 @ Wa1 + ba1); logits = z @ Wa2 + ba2
  gemm_kernel<128, 2, 1><<<NNODES / 64, 256, 0, stream>>>(bufB, Wa1, ba1, bufA);
  gemm_kernel<64, 0, 1><<<NNODES / 64, 256, 0, stream>>>(bufA, Wa2, ba2, sbuf);
  softmax_kernel<<<NNODES / 4, 256, 0, stream>>>(sbuf);

  gather_kernel<<<NNODES / 4, 256, 0, stream>>>(sbuf, offs, ssrc, Gbuf);
  atbA_kernel<<<8 * PB, 512, 0, stream>>>(sbuf, Gbuf, pA);
  atbS_kernel<<<8 * PB, 512, 0, stream>>>(sbuf, outdeg, pS, denp);
  pool_kernel<<<8 * PB, 512, 0, stream>>>(sbuf, bufB, pP);
  merge_kernel<<<256, 512, 0, stream>>>(pA, pS, pP, oadj, ssb, outp);

  gemm_kernel<128, 1, 1><<<512 / 64, 256, 0, stream>>>(outp, Wo, bo, out);
  epilogue_kernel<<<8, 256, 0, stream>>>(oadj, ssb, denp, out);
}

// Round 3
// 457.474 us; speedup vs baseline: 1.4867x; 1.4274x over previous
//
#include <hip/hip_runtime.h>

#define NNODES 32768
#define NEDGES 524288
#define KCL 64

__device__ __forceinline__ float wave_sum(float v) {
#pragma unroll
  for (int off = 32; off > 0; off >>= 1) v += __shfl_xor(v, off, 64);
  return v;
}

__device__ __forceinline__ float wave_max(float v) {
#pragma unroll
  for (int off = 32; off > 0; off >>= 1) v = fmaxf(v, __shfl_xor(v, off, 64));
  return v;
}

// ---------------- edge preprocessing ----------------
__global__ __launch_bounds__(256) void hist_kernel(const int* __restrict__ src, const int* __restrict__ dst,
                                                   int* __restrict__ indeg, int* __restrict__ outdeg) {
  int e = blockIdx.x * 256 + threadIdx.x;
  atomicAdd(&indeg[dst[e]], 1);
  atomicAdd(&outdeg[src[e]], 1);
}

__global__ __launch_bounds__(1024) void scan_kernel(const int* __restrict__ indeg, int* __restrict__ offs,
                                                    int* __restrict__ cursor, float* __restrict__ dis) {
  __shared__ int part[1024];
  int t = threadIdx.x;
  int base = t * 32;
  int loc[32];
  int s = 0;
#pragma unroll
  for (int i = 0; i < 32; i++) { loc[i] = indeg[base + i]; s += loc[i]; }
  part[t] = s;
  __syncthreads();
  for (int off = 1; off < 1024; off <<= 1) {
    int add = (t >= off) ? part[t - off] : 0;
    __syncthreads();
    part[t] += add;
    __syncthreads();
  }
  int run = (t == 0) ? 0 : part[t - 1];
#pragma unroll
  for (int i = 0; i < 32; i++) {
    offs[base + i] = run;
    cursor[base + i] = run;
    dis[base + i] = rsqrtf((float)loc[i] + 1.0f);
    run += loc[i];
  }
  if (t == 1023) offs[NNODES] = run;
}

__global__ __launch_bounds__(256) void scatter_kernel(const int* __restrict__ src, const int* __restrict__ dst,
                                                      int* __restrict__ cursor, int* __restrict__ ssrc) {
  int e = blockIdx.x * 256 + threadIdx.x;
  int d = dst[e];
  int pos = atomicAdd(&cursor[d], 1);
  ssrc[pos] = src[e];
}

// ---------------- fp32 GEMM: C[M x BN] = A[M x 128] @ W[128 x BN] (+bias, act) ----------------
template <int BN, int ACT, int BIAS>
__global__ __launch_bounds__(256) void gemm_kernel(const float* __restrict__ A, const float* __restrict__ W,
                                                   const float* __restrict__ bias, float* __restrict__ C) {
  constexpr int CG = BN / 4;
  constexpr int TM = CG / 4;
  __shared__ float As[32][68];
  __shared__ float Ws[32][BN];
  const int t = threadIdx.x;
  const int tn = t % CG;
  const int tm = t / CG;
  const long rowbase = (long)blockIdx.x * 64;
  float acc[TM][4];
#pragma unroll
  for (int i = 0; i < TM; i++)
#pragma unroll
    for (int j = 0; j < 4; j++) acc[i][j] = 0.f;

  for (int k0 = 0; k0 < 128; k0 += 32) {
#pragma unroll
    for (int it = 0; it < 2; it++) {
      int lin = t + it * 256;
      int row = lin >> 3, c4 = lin & 7;
      float4 v = *reinterpret_cast<const float4*>(A + (rowbase + row) * 128 + k0 + c4 * 4);
      As[c4 * 4 + 0][row] = v.x;
      As[c4 * 4 + 1][row] = v.y;
      As[c4 * 4 + 2][row] = v.z;
      As[c4 * 4 + 3][row] = v.w;
    }
#pragma unroll
    for (int it = 0; it < CG / 8; it++) {
      int lin = t + it * 256;
      int row = lin / CG, c4 = lin % CG;
      *reinterpret_cast<float4*>(&Ws[row][c4 * 4]) =
          *reinterpret_cast<const float4*>(W + (size_t)(k0 + row) * BN + c4 * 4);
    }
    __syncthreads();
#pragma unroll
    for (int k = 0; k < 32; k++) {
      float4 wv = *reinterpret_cast<const float4*>(&Ws[k][tn * 4]);
      float a[TM];
#pragma unroll
      for (int i = 0; i < TM; i += 4) {
        float4 av = *reinterpret_cast<const float4*>(&As[k][tm * TM + i]);
        a[i] = av.x; a[i + 1] = av.y; a[i + 2] = av.z; a[i + 3] = av.w;
      }
#pragma unroll
      for (int i = 0; i < TM; i++) {
        acc[i][0] = fmaf(a[i], wv.x, acc[i][0]);
        acc[i][1] = fmaf(a[i], wv.y, acc[i][1]);
        acc[i][2] = fmaf(a[i], wv.z, acc[i][2]);
        acc[i][3] = fmaf(a[i], wv.w, acc[i][3]);
      }
    }
    __syncthreads();
  }
  float4 bv = {0.f, 0.f, 0.f, 0.f};
  if (BIAS) bv = *reinterpret_cast<const float4*>(bias + tn * 4);
#pragma unroll
  for (int i = 0; i < TM; i++) {
    float r0 = acc[i][0] + bv.x, r1 = acc[i][1] + bv.y;
    float r2 = acc[i][2] + bv.z, r3 = acc[i][3] + bv.w;
    if (ACT == 1) { r0 = fmaxf(r0, 0.f); r1 = fmaxf(r1, 0.f); r2 = fmaxf(r2, 0.f); r3 = fmaxf(r3, 0.f); }
    if (ACT == 2) { r0 = tanhf(r0); r1 = tanhf(r1); r2 = tanhf(r2); r3 = tanhf(r3); }
    float4 out4 = {r0, r1, r2, r3};
    *reinterpret_cast<float4*>(C + (rowbase + tm * TM + i) * BN + tn * 4) = out4;
  }
}

// ---------------- GCN aggregation ----------------
__global__ __launch_bounds__(256) void aggregate_kernel(const float* __restrict__ hlin, const float* __restrict__ dis,
                                                        const int* __restrict__ offs, const int* __restrict__ ssrc,
                                                        const float* __restrict__ bias, float* __restrict__ outh,
                                                        int relu) {
  const int lane = threadIdx.x & 63;
  const int node = blockIdx.x * 4 + (threadIdx.x >> 6);
  const int e0 = offs[node], e1 = offs[node + 1];
  float ax = 0.f, ay = 0.f;
  for (int e = e0; e < e1; ++e) {
    int s = ssrc[e];
    float w = dis[s];
    float2 hv = *reinterpret_cast<const float2*>(hlin + (size_t)s * 128 + lane * 2);
    ax = fmaf(hv.x, w, ax);
    ay = fmaf(hv.y, w, ay);
  }
  float dn = dis[node];
  float2 hs = *reinterpret_cast<const float2*>(hlin + (size_t)node * 128 + lane * 2);
  float rx = fmaf(ax, dn, hs.x * dn * dn) + bias[lane * 2];
  float ry = fmaf(ay, dn, hs.y * dn * dn) + bias[lane * 2 + 1];
  if (relu) { rx = fmaxf(rx, 0.f); ry = fmaxf(ry, 0.f); }
  float2 r = {rx, ry};
  *reinterpret_cast<float2*>(outh + (size_t)node * 128 + lane * 2) = r;
}

// ---------------- double softmax over K=64 + per-node den write (no atomics) ----------------
__global__ __launch_bounds__(256) void softmax_kernel(float* __restrict__ s, const int* __restrict__ outdeg,
                                                      float* __restrict__ dn) {
  const int lane = threadIdx.x & 63;
  const int node = blockIdx.x * 4 + (threadIdx.x >> 6);
  float v = s[(size_t)node * KCL + lane];
  float m = wave_max(v);
  float e = __expf(v - m);
  float s1 = e / wave_sum(e);
  float m2 = wave_max(s1);
  float e2 = __expf(s1 - m2);
  float sd = e2 / wave_sum(e2);
  s[(size_t)node * KCL + lane] = sd;
  float q = wave_sum(sd * sd);
  if (lane == 0) dn[node] = q * (float)outdeg[node];
}

// ---------------- G[m] = sum_{src->m} s_d[src] ----------------
__global__ __launch_bounds__(256) void gather_kernel(const float* __restrict__ sd, const int* __restrict__ offs,
                                                     const int* __restrict__ ssrc, float* __restrict__ G) {
  const int lane = threadIdx.x & 63;
  const int node = blockIdx.x * 4 + (threadIdx.x >> 6);
  const int e0 = offs[node], e1 = offs[node + 1];
  float acc = 0.f;
  for (int e = e0; e < e1; ++e) {
    acc += sd[(size_t)ssrc[e] * 64 + lane];
  }
  G[(size_t)node * 64 + lane] = acc;
}

// ---------------- fused rank reduction: C[64 x 256] = s_chunk^T [G | s | h2]  ----------------
// grid: 8 graphs * 32 chunks of 128 nodes; block 512. Register-tiled GEMM, acc[8][4].
__global__ __launch_bounds__(512) void fused_atb_kernel(const float* __restrict__ sd, const float* __restrict__ G,
                                                        const float* __restrict__ h2, float* __restrict__ pF) {
  __shared__ float Xs[32][64];
  __shared__ float Ys[32][256];
  const int t = threadIdx.x;
  const int g = blockIdx.x >> 5, chunk = blockIdx.x & 31;
  const int n0 = g * 4096 + chunk * 128;
  const int rg = t >> 6;   // 0..7: rows rg*8..rg*8+7 (whole wave shares rg -> Xs reads broadcast)
  const int cl = t & 63;   // cols cl*4..cl*4+3 (lanes consecutive -> conflict-free b128)
  float acc[8][4];
#pragma unroll
  for (int r = 0; r < 8; r++)
#pragma unroll
    for (int j = 0; j < 4; j++) acc[r][j] = 0.f;

  for (int kt = 0; kt < 4; ++kt) {
    const int nb = n0 + kt * 32;
    {
      int k = t >> 4, c = (t & 15) * 4;
      *reinterpret_cast<float4*>(&Xs[k][c]) =
          *reinterpret_cast<const float4*>(&sd[(size_t)(nb + k) * 64 + c]);
    }
#pragma unroll
    for (int it = 0; it < 4; ++it) {
      int slot = it * 512 + t;
      int k = slot >> 6, c = (slot & 63) * 4;
      const float* srcp;
      if (c < 64)       srcp = &G[(size_t)(nb + k) * 64 + c];
      else if (c < 128) srcp = &sd[(size_t)(nb + k) * 64 + (c - 64)];
      else              srcp = &h2[(size_t)(nb + k) * 128 + (c - 128)];
      *reinterpret_cast<float4*>(&Ys[k][c]) = *reinterpret_cast<const float4*>(srcp);
    }
    __syncthreads();
#pragma unroll
    for (int k = 0; k < 32; ++k) {
      float4 b4 = *reinterpret_cast<const float4*>(&Ys[k][cl * 4]);
      float4 a0 = *reinterpret_cast<const float4*>(&Xs[k][rg * 8]);
      float4 a1 = *reinterpret_cast<const float4*>(&Xs[k][rg * 8 + 4]);
      float a[8] = {a0.x, a0.y, a0.z, a0.w, a1.x, a1.y, a1.z, a1.w};
#pragma unroll
      for (int r = 0; r < 8; r++) {
        acc[r][0] = fmaf(a[r], b4.x, acc[r][0]);
        acc[r][1] = fmaf(a[r], b4.y, acc[r][1]);
        acc[r][2] = fmaf(a[r], b4.z, acc[r][2]);
        acc[r][3] = fmaf(a[r], b4.w, acc[r][3]);
      }
    }
    __syncthreads();
  }
  float* dst = pF + (size_t)blockIdx.x * 16384;
#pragma unroll
  for (int r = 0; r < 8; r++) {
    float4 o4 = {acc[r][0], acc[r][1], acc[r][2], acc[r][3]};
    *reinterpret_cast<float4*>(&dst[(rg * 8 + r) * 256 + cl * 4]) = o4;
  }
}

// ---------------- merge 32 partials/graph -> oadj, ssb, outp ----------------
__global__ __launch_bounds__(256) void merge_kernel(const float* __restrict__ pF, float* __restrict__ oadj,
                                                    float* __restrict__ ssb, float* __restrict__ outp) {
  int idx = blockIdx.x * 256 + threadIdx.x;  // 32768 float4 slots total
  int g = idx >> 12, o4 = idx & 4095;        // 4096 float4 per graph (64x256)
  float sx = 0.f, sy = 0.f, sz = 0.f, sw = 0.f;
#pragma unroll
  for (int q = 0; q < 32; ++q) {
    float4 v = *reinterpret_cast<const float4*>(pF + (size_t)(g * 32 + q) * 16384 + o4 * 4);
    sx += v.x; sy += v.y; sz += v.z; sw += v.w;
  }
  int row = o4 >> 6;
  int c = (o4 & 63) * 4;
  float4 o = {sx, sy, sz, sw};
  if (c < 64)
    *reinterpret_cast<float4*>(&oadj[g * 4096 + row * 64 + c]) = o;
  else if (c < 128)
    *reinterpret_cast<float4*>(&ssb[g * 4096 + row * 64 + (c - 64)]) = o;
  else
    *reinterpret_cast<float4*>(&outp[g * 8192 + row * 128 + (c - 128)]) = o;
}

// ---------------- losses + adjacency normalization + pooled_batch ----------------
__global__ __launch_bounds__(256) void epilogue_kernel(const float* __restrict__ oadj, const float* __restrict__ ssb,
                                                       const float* __restrict__ dn, float* __restrict__ out) {
  const int b = blockIdx.x, t = threadIdx.x;
  const float* A = oadj + b * 4096;
  const float* S = ssb + b * 4096;
  // mincut_den: sum dn over this graph's 4096 nodes
  float da = 0.f;
#pragma unroll
  for (int i = 0; i < 16; i++) da += dn[b * 4096 + i * 256 + t];
  float dws = wave_sum(da);
  __shared__ float dw[4];
  if ((t & 63) == 0) dw[t >> 6] = dws;

  const int row = t >> 2, p = t & 3;
  float rs = 0.f, tra = 0.f, trs = 0.f, ssq = 0.f;
#pragma unroll
  for (int c = 0; c < 16; c++) {
    int j = p * 16 + c;
    float v = A[row * 64 + j];
    float w = S[row * 64 + j];
    ssq += w * w;
    if (j == row) { tra += v; trs += w; }
    else rs += v;
  }
  __shared__ float red[256];
  __shared__ float rowsum[64];
  red[t] = rs;
  __syncthreads();
  if (p == 0) rowsum[row] = red[t] + red[t + 1] + red[t + 2] + red[t + 3];
  float v1 = wave_sum(tra), v2 = wave_sum(trs), v3 = wave_sum(ssq);
  __shared__ float w1[4], w2[4], w3[4];
  if ((t & 63) == 0) { int w = t >> 6; w1[w] = v1; w2[w] = v2; w3[w] = v3; }
  __syncthreads();
  if (t == 0) {
    float TRA = w1[0] + w1[1] + w1[2] + w1[3];
    float TRS = w2[0] + w2[1] + w2[2] + w2[3];
    float SSQ = w3[0] + w3[1] + w3[2] + w3[3];
    float DEN = dw[0] + dw[1] + dw[2] + dw[3];
    atomicAdd(&out[98816], -(TRA / DEN) * 0.125f);
    float ssn = sqrtf(SSQ);
    atomicAdd(&out[98817], sqrtf(2.0f - TRS / (4.0f * ssn)) * 0.125f);
  }
  float di = sqrtf(rowsum[row]) + 1e-15f;
#pragma unroll
  for (int c = 0; c < 16; c++) {
    int j = p * 16 + c;
    float v = (j == row) ? 0.f : A[row * 64 + j];
    float dj = sqrtf(rowsum[j]) + 1e-15f;
    out[65536 + b * 4096 + row * 64 + j] = v / (di * dj);
  }
  if (t < 64) out[98304 + b * 64 + t] = (float)b;
}

extern "C" void kernel_launch(void* const* d_in, const int* in_sizes, int n_in,
                              void* d_out, int out_size, void* d_ws, size_t ws_size,
                              hipStream_t stream) {
  const float* x   = (const float*)d_in[0];
  const int*   ei  = (const int*)d_in[1];
  const float* W1  = (const float*)d_in[3];
  const float* b1  = (const float*)d_in[4];
  const float* W2  = (const float*)d_in[5];
  const float* b2  = (const float*)d_in[6];
  const float* Wa1 = (const float*)d_in[7];
  const float* ba1 = (const float*)d_in[8];
  const float* Wa2 = (const float*)d_in[9];
  const float* ba2 = (const float*)d_in[10];
  const float* Wo  = (const float*)d_in[11];
  const float* bo  = (const float*)d_in[12];
  const int* src = ei;
  const int* dst = ei + NEDGES;
  float* out = (float*)d_out;

  char* ws = (char*)d_ws;
  size_t o = 0;
  auto alloc = [&](size_t bytes) -> void* {
    void* p = ws + o;
    o += (bytes + 255) & ~(size_t)255;
    return p;
  };
  float* bufA  = (float*)alloc((size_t)NNODES * 128 * 4);  // 16 MB (reused as pF)
  float* bufB  = (float*)alloc((size_t)NNODES * 128 * 4);  // 16 MB
  float* sbuf  = (float*)alloc((size_t)NNODES * 64 * 4);   // 8 MB
  float* Gbuf  = (float*)alloc((size_t)NNODES * 64 * 4);   // 8 MB
  float* dis   = (float*)alloc((size_t)NNODES * 4);
  int* indeg   = (int*)alloc((size_t)NNODES * 4);
  int* outdeg  = (int*)alloc((size_t)NNODES * 4);
  int* offs    = (int*)alloc((size_t)(NNODES + 1) * 4);
  int* cursor  = (int*)alloc((size_t)NNODES * 4);
  int* ssrc    = (int*)alloc((size_t)NEDGES * 4);
  float* dn    = (float*)alloc((size_t)NNODES * 4);
  float* oadj  = (float*)alloc(8 * 4096 * 4);
  float* ssb   = (float*)alloc(8 * 4096 * 4);
  float* outp  = (float*)alloc(8 * 8192 * 4);
  float* pF    = bufA;  // 256 blocks * 16384 floats = 16 MB, aliases bufA (dead by then)

  hipMemsetAsync(d_out, 0, (size_t)out_size * 4, stream);
  hipMemsetAsync(indeg, 0, (size_t)NNODES * 4, stream);
  hipMemsetAsync(outdeg, 0, (size_t)NNODES * 4, stream);

  hist_kernel<<<NEDGES / 256, 256, 0, stream>>>(src, dst, indeg, outdeg);
  scan_kernel<<<1, 1024, 0, stream>>>(indeg, offs, cursor, dis);
  scatter_kernel<<<NEDGES / 256, 256, 0, stream>>>(src, dst, cursor, ssrc);

  // GCN layer 1: h1 = relu(agg(x @ W1) + b1)
  gemm_kernel<128, 0, 0><<<NNODES / 64, 256, 0, stream>>>(x, W1, nullptr, bufA);
  aggregate_kernel<<<NNODES / 4, 256, 0, stream>>>(bufA, dis, offs, ssrc, b1, bufB, 1);
  // GCN layer 2: h2 = agg(h1 @ W2) + b2
  gemm_kernel<128, 0, 0><<<NNODES / 64, 256, 0, stream>>>(bufB, W2, nullptr, bufA);
  aggregate_kernel<<<NNODES / 4, 256, 0, stream>>>(bufA, dis, offs, ssrc, b2, bufB, 0);

  // assignment MLP: z = tanh(h2 @ Wa1 + ba1); logits = z @ Wa2 + ba2
  gemm_kernel<128, 2, 1><<<NNODES / 64, 256, 0, stream>>>(bufB, Wa1, ba1, bufA);
  gemm_kernel<64, 0, 1><<<NNODES / 64, 256, 0, stream>>>(bufA, Wa2, ba2, sbuf);
  softmax_kernel<<<NNODES / 4, 256, 0, stream>>>(sbuf, outdeg, dn);

  gather_kernel<<<NNODES / 4, 256, 0, stream>>>(sbuf, offs, ssrc, Gbuf);
  // fused s^T [G | s | h2] over 8*32 chunks (pF aliases bufA, dead after logits gemm)
  fused_atb_kernel<<<256, 512, 0, stream>>>(sbuf, Gbuf, bufB, pF);
  merge_kernel<<<128, 256, 0, stream>>>(pF, oadj, ssb, outp);

  gemm_kernel<128, 1, 1><<<512 / 64, 256, 0, stream>>>(outp, Wo, bo, out);
  epilogue_kernel<<<8, 256, 0, stream>>>(oadj, ssb, dn, out);
}

// Round 4
// 368.139 us; speedup vs baseline: 1.8475x; 1.2427x over previous
//
#include <hip/hip_runtime.h>

#define NNODES 32768
#define NEDGES 524288
#define KCL 64

__device__ __forceinline__ float wave_sum(float v) {
#pragma unroll
  for (int off = 32; off > 0; off >>= 1) v += __shfl_xor(v, off, 64);
  return v;
}

__device__ __forceinline__ float wave_max(float v) {
#pragma unroll
  for (int off = 32; off > 0; off >>= 1) v = fmaxf(v, __shfl_xor(v, off, 64));
  return v;
}

// ---------------- edge preprocessing ----------------
__global__ __launch_bounds__(256) void hist_kernel(const int* __restrict__ src, const int* __restrict__ dst,
                                                   int* __restrict__ indeg, int* __restrict__ outdeg) {
  int e = blockIdx.x * 256 + threadIdx.x;
  atomicAdd(&indeg[dst[e]], 1);
  atomicAdd(&outdeg[src[e]], 1);
}

__global__ __launch_bounds__(1024) void scan_kernel(const int* __restrict__ indeg, int* __restrict__ offs,
                                                    int* __restrict__ cursor, float* __restrict__ dis) {
  __shared__ int part[1024];
  int t = threadIdx.x;
  int base = t * 32;
  int loc[32];
  int s = 0;
#pragma unroll
  for (int i = 0; i < 32; i++) { loc[i] = indeg[base + i]; s += loc[i]; }
  part[t] = s;
  __syncthreads();
  for (int off = 1; off < 1024; off <<= 1) {
    int add = (t >= off) ? part[t - off] : 0;
    __syncthreads();
    part[t] += add;
    __syncthreads();
  }
  int run = (t == 0) ? 0 : part[t - 1];
#pragma unroll
  for (int i = 0; i < 32; i++) {
    offs[base + i] = run;
    cursor[base + i] = run;
    dis[base + i] = rsqrtf((float)loc[i] + 1.0f);
    run += loc[i];
  }
  if (t == 1023) offs[NNODES] = run;
}

__global__ __launch_bounds__(256) void scatter_kernel(const int* __restrict__ src, const int* __restrict__ dst,
                                                      int* __restrict__ cursor, int* __restrict__ ssrc) {
  int e = blockIdx.x * 256 + threadIdx.x;
  int d = dst[e];
  int pos = atomicAdd(&cursor[d], 1);
  ssrc[pos] = src[e];
}

// ---------------- fp32 GEMM: C[M x BN] = A[M x 128] @ W[128 x BN] (+bias, act, row-scale) ----------------
template <int BN, int ACT, int BIAS, int SCALE>
__global__ __launch_bounds__(256) void gemm_kernel(const float* __restrict__ A, const float* __restrict__ W,
                                                   const float* __restrict__ bias, const float* __restrict__ rowscale,
                                                   float* __restrict__ C) {
  constexpr int CG = BN / 4;
  constexpr int TM = CG / 4;
  __shared__ float As[32][68];
  __shared__ float Ws[32][BN];
  const int t = threadIdx.x;
  const int tn = t % CG;
  const int tm = t / CG;
  const long rowbase = (long)blockIdx.x * 64;
  float acc[TM][4];
#pragma unroll
  for (int i = 0; i < TM; i++)
#pragma unroll
    for (int j = 0; j < 4; j++) acc[i][j] = 0.f;

  for (int k0 = 0; k0 < 128; k0 += 32) {
#pragma unroll
    for (int it = 0; it < 2; it++) {
      int lin = t + it * 256;
      int row = lin >> 3, c4 = lin & 7;
      float4 v = *reinterpret_cast<const float4*>(A + (rowbase + row) * 128 + k0 + c4 * 4);
      As[c4 * 4 + 0][row] = v.x;
      As[c4 * 4 + 1][row] = v.y;
      As[c4 * 4 + 2][row] = v.z;
      As[c4 * 4 + 3][row] = v.w;
    }
#pragma unroll
    for (int it = 0; it < CG / 8; it++) {
      int lin = t + it * 256;
      int row = lin / CG, c4 = lin % CG;
      *reinterpret_cast<float4*>(&Ws[row][c4 * 4]) =
          *reinterpret_cast<const float4*>(W + (size_t)(k0 + row) * BN + c4 * 4);
    }
    __syncthreads();
#pragma unroll
    for (int k = 0; k < 32; k++) {
      float4 wv = *reinterpret_cast<const float4*>(&Ws[k][tn * 4]);
      float a[TM];
#pragma unroll
      for (int i = 0; i < TM; i += 4) {
        float4 av = *reinterpret_cast<const float4*>(&As[k][tm * TM + i]);
        a[i] = av.x; a[i + 1] = av.y; a[i + 2] = av.z; a[i + 3] = av.w;
      }
#pragma unroll
      for (int i = 0; i < TM; i++) {
        acc[i][0] = fmaf(a[i], wv.x, acc[i][0]);
        acc[i][1] = fmaf(a[i], wv.y, acc[i][1]);
        acc[i][2] = fmaf(a[i], wv.z, acc[i][2]);
        acc[i][3] = fmaf(a[i], wv.w, acc[i][3]);
      }
    }
    __syncthreads();
  }
  float4 bv = {0.f, 0.f, 0.f, 0.f};
  if (BIAS) bv = *reinterpret_cast<const float4*>(bias + tn * 4);
#pragma unroll
  for (int i = 0; i < TM; i++) {
    float sc = SCALE ? rowscale[rowbase + tm * TM + i] : 1.0f;
    float r0 = acc[i][0], r1 = acc[i][1], r2 = acc[i][2], r3 = acc[i][3];
    if (SCALE) { r0 *= sc; r1 *= sc; r2 *= sc; r3 *= sc; }
    r0 += bv.x; r1 += bv.y; r2 += bv.z; r3 += bv.w;
    if (ACT == 1) { r0 = fmaxf(r0, 0.f); r1 = fmaxf(r1, 0.f); r2 = fmaxf(r2, 0.f); r3 = fmaxf(r3, 0.f); }
    if (ACT == 2) { r0 = tanhf(r0); r1 = tanhf(r1); r2 = tanhf(r2); r3 = tanhf(r3); }
    float4 out4 = {r0, r1, r2, r3};
    *reinterpret_cast<float4*>(C + (rowbase + tm * TM + i) * BN + tn * 4) = out4;
  }
}

// ---------------- GCN aggregation over pre-scaled hs (hs[r] = dis[r] * (x@W)[r]) ----------------
// out[n] = dis[n] * (sum_{src->n} hs[src] + hs[n]) + b ; one wave per node, 2 edges per float4 load.
__global__ __launch_bounds__(256) void aggregate_kernel(const float* __restrict__ hs, const float* __restrict__ dis,
                                                        const int* __restrict__ offs, const int* __restrict__ ssrc,
                                                        const float* __restrict__ bias, float* __restrict__ outh,
                                                        int relu) {
  const int lane = threadIdx.x & 63;
  const int node = blockIdx.x * 4 + (threadIdx.x >> 6);
  const int half = lane >> 5;        // 0/1: which edge of the pair
  const int fl = (lane & 31) * 4;    // feature offset (32 lanes cover 128 floats)
  const int e0 = offs[node], e1 = offs[node + 1];
  float4 acc = {0.f, 0.f, 0.f, 0.f};
  int e = e0;
  // main: 8 edges per iteration (4 pairs in flight)
  for (; e + 8 <= e1; e += 8) {
    int s0 = ssrc[e + half];
    int s1 = ssrc[e + 2 + half];
    int s2 = ssrc[e + 4 + half];
    int s3 = ssrc[e + 6 + half];
    float4 v0 = *reinterpret_cast<const float4*>(hs + (size_t)s0 * 128 + fl);
    float4 v1 = *reinterpret_cast<const float4*>(hs + (size_t)s1 * 128 + fl);
    float4 v2 = *reinterpret_cast<const float4*>(hs + (size_t)s2 * 128 + fl);
    float4 v3 = *reinterpret_cast<const float4*>(hs + (size_t)s3 * 128 + fl);
    acc.x += v0.x + v1.x + v2.x + v3.x;
    acc.y += v0.y + v1.y + v2.y + v3.y;
    acc.z += v0.z + v1.z + v2.z + v3.z;
    acc.w += v0.w + v1.w + v2.w + v3.w;
  }
  // tail: 2 edges per iteration, masked
  for (; e < e1; e += 2) {
    int idx = e + half;
    bool valid = idx < e1;
    int s = valid ? ssrc[idx] : node;
    float4 v = *reinterpret_cast<const float4*>(hs + (size_t)s * 128 + fl);
    if (valid) { acc.x += v.x; acc.y += v.y; acc.z += v.z; acc.w += v.w; }
  }
  // reduce the two halves
  acc.x += __shfl_xor(acc.x, 32, 64);
  acc.y += __shfl_xor(acc.y, 32, 64);
  acc.z += __shfl_xor(acc.z, 32, 64);
  acc.w += __shfl_xor(acc.w, 32, 64);
  if (half == 0) {
    float dn = dis[node];
    float4 self = *reinterpret_cast<const float4*>(hs + (size_t)node * 128 + fl);
    float4 bv = *reinterpret_cast<const float4*>(bias + fl);
    float r0 = fmaf(acc.x + self.x, dn, bv.x);
    float r1 = fmaf(acc.y + self.y, dn, bv.y);
    float r2 = fmaf(acc.z + self.z, dn, bv.z);
    float r3 = fmaf(acc.w + self.w, dn, bv.w);
    if (relu) { r0 = fmaxf(r0, 0.f); r1 = fmaxf(r1, 0.f); r2 = fmaxf(r2, 0.f); r3 = fmaxf(r3, 0.f); }
    float4 r = {r0, r1, r2, r3};
    *reinterpret_cast<float4*>(outh + (size_t)node * 128 + fl) = r;
  }
}

// ---------------- double softmax over K=64 + per-node den write ----------------
__global__ __launch_bounds__(256) void softmax_kernel(float* __restrict__ s, const int* __restrict__ outdeg,
                                                      float* __restrict__ dn) {
  const int lane = threadIdx.x & 63;
  const int node = blockIdx.x * 4 + (threadIdx.x >> 6);
  float v = s[(size_t)node * KCL + lane];
  float m = wave_max(v);
  float e = __expf(v - m);
  float s1 = e / wave_sum(e);
  float m2 = wave_max(s1);
  float e2 = __expf(s1 - m2);
  float sd = e2 / wave_sum(e2);
  s[(size_t)node * KCL + lane] = sd;
  float q = wave_sum(sd * sd);
  if (lane == 0) dn[node] = q * (float)outdeg[node];
}

// ---------------- G[m] = sum_{src->m} s_d[src]  (4 edges per float4 load) ----------------
__global__ __launch_bounds__(256) void gather_kernel(const float* __restrict__ sd, const int* __restrict__ offs,
                                                     const int* __restrict__ ssrc, float* __restrict__ G) {
  const int lane = threadIdx.x & 63;
  const int node = blockIdx.x * 4 + (threadIdx.x >> 6);
  const int q = lane >> 4;           // 0..3: edge slot
  const int fl = (lane & 15) * 4;    // 16 lanes cover 64 floats
  const int e0 = offs[node], e1 = offs[node + 1];
  float4 acc = {0.f, 0.f, 0.f, 0.f};
  int e = e0;
  for (; e + 8 <= e1; e += 8) {
    int s0 = ssrc[e + q];
    int s1 = ssrc[e + 4 + q];
    float4 v0 = *reinterpret_cast<const float4*>(sd + (size_t)s0 * 64 + fl);
    float4 v1 = *reinterpret_cast<const float4*>(sd + (size_t)s1 * 64 + fl);
    acc.x += v0.x + v1.x;
    acc.y += v0.y + v1.y;
    acc.z += v0.z + v1.z;
    acc.w += v0.w + v1.w;
  }
  for (; e < e1; e += 4) {
    int idx = e + q;
    bool valid = idx < e1;
    int s = valid ? ssrc[idx] : node;
    float4 v = *reinterpret_cast<const float4*>(sd + (size_t)s * 64 + fl);
    if (valid) { acc.x += v.x; acc.y += v.y; acc.z += v.z; acc.w += v.w; }
  }
#pragma unroll
  for (int off = 16; off <= 32; off <<= 1) {
    acc.x += __shfl_xor(acc.x, off, 64);
    acc.y += __shfl_xor(acc.y, off, 64);
    acc.z += __shfl_xor(acc.z, off, 64);
    acc.w += __shfl_xor(acc.w, off, 64);
  }
  if (q == 0) {
    *reinterpret_cast<float4*>(G + (size_t)node * 64 + fl) = acc;
  }
}

// ---------------- fused rank reduction: C[64 x 256] = s_chunk^T [G | s | h2] ----------------
__global__ __launch_bounds__(512) void fused_atb_kernel(const float* __restrict__ sd, const float* __restrict__ G,
                                                        const float* __restrict__ h2, float* __restrict__ pF) {
  __shared__ float Xs[32][64];
  __shared__ float Ys[32][256];
  const int t = threadIdx.x;
  const int g = blockIdx.x >> 5, chunk = blockIdx.x & 31;
  const int n0 = g * 4096 + chunk * 128;
  const int rg = t >> 6;
  const int cl = t & 63;
  float acc[8][4];
#pragma unroll
  for (int r = 0; r < 8; r++)
#pragma unroll
    for (int j = 0; j < 4; j++) acc[r][j] = 0.f;

  for (int kt = 0; kt < 4; ++kt) {
    const int nb = n0 + kt * 32;
    {
      int k = t >> 4, c = (t & 15) * 4;
      *reinterpret_cast<float4*>(&Xs[k][c]) =
          *reinterpret_cast<const float4*>(&sd[(size_t)(nb + k) * 64 + c]);
    }
#pragma unroll
    for (int it = 0; it < 4; ++it) {
      int slot = it * 512 + t;
      int k = slot >> 6, c = (slot & 63) * 4;
      const float* srcp;
      if (c < 64)       srcp = &G[(size_t)(nb + k) * 64 + c];
      else if (c < 128) srcp = &sd[(size_t)(nb + k) * 64 + (c - 64)];
      else              srcp = &h2[(size_t)(nb + k) * 128 + (c - 128)];
      *reinterpret_cast<float4*>(&Ys[k][c]) = *reinterpret_cast<const float4*>(srcp);
    }
    __syncthreads();
#pragma unroll
    for (int k = 0; k < 32; ++k) {
      float4 b4 = *reinterpret_cast<const float4*>(&Ys[k][cl * 4]);
      float4 a0 = *reinterpret_cast<const float4*>(&Xs[k][rg * 8]);
      float4 a1 = *reinterpret_cast<const float4*>(&Xs[k][rg * 8 + 4]);
      float a[8] = {a0.x, a0.y, a0.z, a0.w, a1.x, a1.y, a1.z, a1.w};
#pragma unroll
      for (int r = 0; r < 8; r++) {
        acc[r][0] = fmaf(a[r], b4.x, acc[r][0]);
        acc[r][1] = fmaf(a[r], b4.y, acc[r][1]);
        acc[r][2] = fmaf(a[r], b4.z, acc[r][2]);
        acc[r][3] = fmaf(a[r], b4.w, acc[r][3]);
      }
    }
    __syncthreads();
  }
  float* dst = pF + (size_t)blockIdx.x * 16384;
#pragma unroll
  for (int r = 0; r < 8; r++) {
    float4 o4 = {acc[r][0], acc[r][1], acc[r][2], acc[r][3]};
    *reinterpret_cast<float4*>(&dst[(rg * 8 + r) * 256 + cl * 4]) = o4;
  }
}

// ---------------- merge 32 partials/graph -> oadj, ssb, outp ----------------
__global__ __launch_bounds__(256) void merge_kernel(const float* __restrict__ pF, float* __restrict__ oadj,
                                                    float* __restrict__ ssb, float* __restrict__ outp) {
  int idx = blockIdx.x * 256 + threadIdx.x;
  int g = idx >> 12, o4 = idx & 4095;
  float sx = 0.f, sy = 0.f, sz = 0.f, sw = 0.f;
#pragma unroll
  for (int q = 0; q < 32; ++q) {
    float4 v = *reinterpret_cast<const float4*>(pF + (size_t)(g * 32 + q) * 16384 + o4 * 4);
    sx += v.x; sy += v.y; sz += v.z; sw += v.w;
  }
  int row = o4 >> 6;
  int c = (o4 & 63) * 4;
  float4 o = {sx, sy, sz, sw};
  if (c < 64)
    *reinterpret_cast<float4*>(&oadj[g * 4096 + row * 64 + c]) = o;
  else if (c < 128)
    *reinterpret_cast<float4*>(&ssb[g * 4096 + row * 64 + (c - 64)]) = o;
  else
    *reinterpret_cast<float4*>(&outp[g * 8192 + row * 128 + (c - 128)]) = o;
}

// ---------------- losses + adjacency normalization + pooled_batch ----------------
__global__ __launch_bounds__(256) void epilogue_kernel(const float* __restrict__ oadj, const float* __restrict__ ssb,
                                                       const float* __restrict__ dn, float* __restrict__ out) {
  const int b = blockIdx.x, t = threadIdx.x;
  const float* A = oadj + b * 4096;
  const float* S = ssb + b * 4096;
  float da = 0.f;
#pragma unroll
  for (int i = 0; i < 16; i++) da += dn[b * 4096 + i * 256 + t];
  float dws = wave_sum(da);
  __shared__ float dw[4];
  if ((t & 63) == 0) dw[t >> 6] = dws;

  const int row = t >> 2, p = t & 3;
  float rs = 0.f, tra = 0.f, trs = 0.f, ssq = 0.f;
#pragma unroll
  for (int c = 0; c < 16; c++) {
    int j = p * 16 + c;
    float v = A[row * 64 + j];
    float w = S[row * 64 + j];
    ssq += w * w;
    if (j == row) { tra += v; trs += w; }
    else rs += v;
  }
  __shared__ float red[256];
  __shared__ float rowsum[64];
  red[t] = rs;
  __syncthreads();
  if (p == 0) rowsum[row] = red[t] + red[t + 1] + red[t + 2] + red[t + 3];
  float v1 = wave_sum(tra), v2 = wave_sum(trs), v3 = wave_sum(ssq);
  __shared__ float w1[4], w2[4], w3[4];
  if ((t & 63) == 0) { int w = t >> 6; w1[w] = v1; w2[w] = v2; w3[w] = v3; }
  __syncthreads();
  if (t == 0) {
    float TRA = w1[0] + w1[1] + w1[2] + w1[3];
    float TRS = w2[0] + w2[1] + w2[2] + w2[3];
    float SSQ = w3[0] + w3[1] + w3[2] + w3[3];
    float DEN = dw[0] + dw[1] + dw[2] + dw[3];
    atomicAdd(&out[98816], -(TRA / DEN) * 0.125f);
    float ssn = sqrtf(SSQ);
    atomicAdd(&out[98817], sqrtf(2.0f - TRS / (4.0f * ssn)) * 0.125f);
  }
  float di = sqrtf(rowsum[row]) + 1e-15f;
#pragma unroll
  for (int c = 0; c < 16; c++) {
    int j = p * 16 + c;
    float v = (j == row) ? 0.f : A[row * 64 + j];
    float dj = sqrtf(rowsum[j]) + 1e-15f;
    out[65536 + b * 4096 + row * 64 + j] = v / (di * dj);
  }
  if (t < 64) out[98304 + b * 64 + t] = (float)b;
}

extern "C" void kernel_launch(void* const* d_in, const int* in_sizes, int n_in,
                              void* d_out, int out_size, void* d_ws, size_t ws_size,
                              hipStream_t stream) {
  const float* x   = (const float*)d_in[0];
  const int*   ei  = (const int*)d_in[1];
  const float* W1  = (const float*)d_in[3];
  const float* b1  = (const float*)d_in[4];
  const float* W2  = (const float*)d_in[5];
  const float* b2  = (const float*)d_in[6];
  const float* Wa1 = (const float*)d_in[7];
  const float* ba1 = (const float*)d_in[8];
  const float* Wa2 = (const float*)d_in[9];
  const float* ba2 = (const float*)d_in[10];
  const float* Wo  = (const float*)d_in[11];
  const float* bo  = (const float*)d_in[12];
  const int* src = ei;
  const int* dst = ei + NEDGES;
  float* out = (float*)d_out;

  char* ws = (char*)d_ws;
  size_t o = 0;
  auto alloc = [&](size_t bytes) -> void* {
    void* p = ws + o;
    o += (bytes + 255) & ~(size_t)255;
    return p;
  };
  float* bufA  = (float*)alloc((size_t)NNODES * 128 * 4);  // 16 MB (reused as pF)
  float* bufB  = (float*)alloc((size_t)NNODES * 128 * 4);  // 16 MB
  float* sbuf  = (float*)alloc((size_t)NNODES * 64 * 4);   // 8 MB
  float* Gbuf  = (float*)alloc((size_t)NNODES * 64 * 4);   // 8 MB
  float* dis   = (float*)alloc((size_t)NNODES * 4);
  int* indeg   = (int*)alloc((size_t)NNODES * 4);
  int* outdeg  = (int*)alloc((size_t)NNODES * 4);
  int* offs    = (int*)alloc((size_t)(NNODES + 1) * 4);
  int* cursor  = (int*)alloc((size_t)NNODES * 4);
  int* ssrc    = (int*)alloc((size_t)NEDGES * 4);
  float* dn    = (float*)alloc((size_t)NNODES * 4);
  float* oadj  = (float*)alloc(8 * 4096 * 4);
  float* ssb   = (float*)alloc(8 * 4096 * 4);
  float* outp  = (float*)alloc(8 * 8192 * 4);
  float* pF    = bufA;  // aliases bufA (dead by then)

  hipMemsetAsync(d_out, 0, (size_t)out_size * 4, stream);
  hipMemsetAsync(indeg, 0, (size_t)NNODES * 4, stream);
  hipMemsetAsync(outdeg, 0, (size_t)NNODES * 4, stream);

  hist_kernel<<<NEDGES / 256, 256, 0, stream>>>(src, dst, indeg, outdeg);
  scan_kernel<<<1, 1024, 0, stream>>>(indeg, offs, cursor, dis);
  scatter_kernel<<<NEDGES / 256, 256, 0, stream>>>(src, dst, cursor, ssrc);

  // GCN layer 1: hs = dis .* (x @ W1); h1 = relu(dis_n*(sum hs + hs_n) + b1)
  gemm_kernel<128, 0, 0, 1><<<NNODES / 64, 256, 0, stream>>>(x, W1, nullptr, dis, bufA);
  aggregate_kernel<<<NNODES / 4, 256, 0, stream>>>(bufA, dis, offs, ssrc, b1, bufB, 1);
  // GCN layer 2
  gemm_kernel<128, 0, 0, 1><<<NNODES / 64, 256, 0, stream>>>(bufB, W2, nullptr, dis, bufA);
  aggregate_kernel<<<NNODES / 4, 256, 0, stream>>>(bufA, dis, offs, ssrc, b2, bufB, 0);

  // assignment MLP
  gemm_kernel<128, 2, 1, 0><<<NNODES / 64, 256, 0, stream>>>(bufB, Wa1, ba1, nullptr, bufA);
  gemm_kernel<64, 0, 1, 0><<<NNODES / 64, 256, 0, stream>>>(bufA, Wa2, ba2, nullptr, sbuf);
  softmax_kernel<<<NNODES / 4, 256, 0, stream>>>(sbuf, outdeg, dn);

  gather_kernel<<<NNODES / 4, 256, 0, stream>>>(sbuf, offs, ssrc, Gbuf);
  fused_atb_kernel<<<256, 512, 0, stream>>>(sbuf, Gbuf, bufB, pF);
  merge_kernel<<<128, 256, 0, stream>>>(pF, oadj, ssb, outp);

  gemm_kernel<128, 1, 1, 0><<<512 / 64, 256, 0, stream>>>(outp, Wo, bo, nullptr, out);
  epilogue_kernel<<<8, 256, 0, stream>>>(oadj, ssb, dn, out);
}

// Round 5
// 313.301 us; speedup vs baseline: 2.1709x; 1.1750x over previous
//
#include <hip/hip_runtime.h>

#define NNODES 32768
#define NEDGES 524288
#define KCL 64
// edge layout: 65536 edges per graph, contiguous; node ids within graph g in [g*4096,(g+1)*4096)
#define CPG 16   // histogram chunks per graph (4096 edges each)

__device__ __forceinline__ float wave_sum(float v) {
#pragma unroll
  for (int off = 32; off > 0; off >>= 1) v += __shfl_xor(v, off, 64);
  return v;
}

__device__ __forceinline__ float wave_max(float v) {
#pragma unroll
  for (int off = 32; off > 0; off >>= 1) v = fmaxf(v, __shfl_xor(v, off, 64));
  return v;
}

// ---------------- per-chunk LDS histograms (no global atomics) ----------------
__global__ __launch_bounds__(256) void hist2_kernel(const int* __restrict__ src, const int* __restrict__ dst,
                                                    int* __restrict__ pIn, int* __restrict__ pOut) {
  __shared__ int hIn[4096];
  __shared__ int hOut[4096];
  const int t = threadIdx.x;
  const int g = blockIdx.x >> 4;
  const int ebase = (g << 16) + ((blockIdx.x & 15) << 12);
  const int nbase = g << 12;
  for (int i = t; i < 4096; i += 256) { hIn[i] = 0; hOut[i] = 0; }
  __syncthreads();
#pragma unroll
  for (int i = 0; i < 16; ++i) {
    int e = ebase + i * 256 + t;
    atomicAdd(&hIn[dst[e] - nbase], 1);
    atomicAdd(&hOut[src[e] - nbase], 1);
  }
  __syncthreads();
  int* dIn = pIn + ((size_t)blockIdx.x << 12);
  int* dOut = pOut + ((size_t)blockIdx.x << 12);
  for (int i = t; i < 4096; i += 256) { dIn[i] = hIn[i]; dOut[i] = hOut[i]; }
}

// ---------------- per-graph scan: offs, dis, outdeg, per-chunk cursor bases ----------------
__global__ __launch_bounds__(1024) void scan2_kernel(const int* __restrict__ pIn, const int* __restrict__ pOut,
                                                     int* __restrict__ offs, int* __restrict__ cbase,
                                                     int* __restrict__ outdeg, float* __restrict__ dis) {
  __shared__ int part[1024];
  const int t = threadIdx.x;
  const int g = blockIdx.x;
  int tot[4];
  int s = 0;
#pragma unroll
  for (int j = 0; j < 4; ++j) {
    int l = t * 4 + j;
    int cnt = 0;
#pragma unroll
    for (int c = 0; c < CPG; ++c) cnt += pIn[(((size_t)(g * CPG + c)) << 12) + l];
    tot[j] = cnt;
    s += cnt;
  }
  part[t] = s;
  __syncthreads();
  for (int off = 1; off < 1024; off <<= 1) {
    int add = (t >= off) ? part[t - off] : 0;
    __syncthreads();
    part[t] += add;
    __syncthreads();
  }
  int run = (g << 16) + ((t == 0) ? 0 : part[t - 1]);
#pragma unroll
  for (int j = 0; j < 4; ++j) {
    int l = t * 4 + j;
    int n = (g << 12) + l;
    offs[n] = run;
    dis[n] = rsqrtf((float)tot[j] + 1.0f);
    int od = 0;
#pragma unroll
    for (int c = 0; c < CPG; ++c) od += pOut[(((size_t)(g * CPG + c)) << 12) + l];
    outdeg[n] = od;
    int running = run;
#pragma unroll
    for (int c = 0; c < CPG; ++c) {
      size_t idx = (((size_t)(g * CPG + c)) << 12) + l;
      cbase[idx] = running;
      running += pIn[idx];
    }
    run += tot[j];
  }
  if (g == 0 && t == 0) offs[NNODES] = NEDGES;
}

// ---------------- scatter via LDS cursors (no global atomics) ----------------
__global__ __launch_bounds__(256) void scatter2_kernel(const int* __restrict__ src, const int* __restrict__ dst,
                                                       const int* __restrict__ cbase, int* __restrict__ ssrc) {
  __shared__ int cur[4096];
  const int t = threadIdx.x;
  const int g = blockIdx.x >> 4;
  const int ebase = (g << 16) + ((blockIdx.x & 15) << 12);
  const int nbase = g << 12;
  const int* cb = cbase + ((size_t)blockIdx.x << 12);
  for (int i = t; i < 4096; i += 256) cur[i] = cb[i];
  __syncthreads();
#pragma unroll
  for (int i = 0; i < 16; ++i) {
    int e = ebase + i * 256 + t;
    int d = dst[e] - nbase;
    int pos = atomicAdd(&cur[d], 1);
    ssrc[pos] = src[e];
  }
}

// ---------------- fp32 GEMM: C[M x BN] = A[M x 128] @ W[128 x BN] (+bias, act, row-scale) ----------------
template <int BN, int ACT, int BIAS, int SCALE>
__global__ __launch_bounds__(256) void gemm_kernel(const float* __restrict__ A, const float* __restrict__ W,
                                                   const float* __restrict__ bias, const float* __restrict__ rowscale,
                                                   float* __restrict__ C) {
  constexpr int CG = BN / 4;
  constexpr int TM = CG / 4;
  __shared__ float As[32][68];
  __shared__ float Ws[32][BN];
  const int t = threadIdx.x;
  const int tn = t % CG;
  const int tm = t / CG;
  const long rowbase = (long)blockIdx.x * 64;
  float acc[TM][4];
#pragma unroll
  for (int i = 0; i < TM; i++)
#pragma unroll
    for (int j = 0; j < 4; j++) acc[i][j] = 0.f;

  for (int k0 = 0; k0 < 128; k0 += 32) {
#pragma unroll
    for (int it = 0; it < 2; it++) {
      int lin = t + it * 256;
      int row = lin >> 3, c4 = lin & 7;
      float4 v = *reinterpret_cast<const float4*>(A + (rowbase + row) * 128 + k0 + c4 * 4);
      As[c4 * 4 + 0][row] = v.x;
      As[c4 * 4 + 1][row] = v.y;
      As[c4 * 4 + 2][row] = v.z;
      As[c4 * 4 + 3][row] = v.w;
    }
#pragma unroll
    for (int it = 0; it < CG / 8; it++) {
      int lin = t + it * 256;
      int row = lin / CG, c4 = lin % CG;
      *reinterpret_cast<float4*>(&Ws[row][c4 * 4]) =
          *reinterpret_cast<const float4*>(W + (size_t)(k0 + row) * BN + c4 * 4);
    }
    __syncthreads();
#pragma unroll
    for (int k = 0; k < 32; k++) {
      float4 wv = *reinterpret_cast<const float4*>(&Ws[k][tn * 4]);
      float a[TM];
#pragma unroll
      for (int i = 0; i < TM; i += 4) {
        float4 av = *reinterpret_cast<const float4*>(&As[k][tm * TM + i]);
        a[i] = av.x; a[i + 1] = av.y; a[i + 2] = av.z; a[i + 3] = av.w;
      }
#pragma unroll
      for (int i = 0; i < TM; i++) {
        acc[i][0] = fmaf(a[i], wv.x, acc[i][0]);
        acc[i][1] = fmaf(a[i], wv.y, acc[i][1]);
        acc[i][2] = fmaf(a[i], wv.z, acc[i][2]);
        acc[i][3] = fmaf(a[i], wv.w, acc[i][3]);
      }
    }
    __syncthreads();
  }
  float4 bv = {0.f, 0.f, 0.f, 0.f};
  if (BIAS) bv = *reinterpret_cast<const float4*>(bias + tn * 4);
#pragma unroll
  for (int i = 0; i < TM; i++) {
    float sc = SCALE ? rowscale[rowbase + tm * TM + i] : 1.0f;
    float r0 = acc[i][0], r1 = acc[i][1], r2 = acc[i][2], r3 = acc[i][3];
    if (SCALE) { r0 *= sc; r1 *= sc; r2 *= sc; r3 *= sc; }
    r0 += bv.x; r1 += bv.y; r2 += bv.z; r3 += bv.w;
    if (ACT == 1) { r0 = fmaxf(r0, 0.f); r1 = fmaxf(r1, 0.f); r2 = fmaxf(r2, 0.f); r3 = fmaxf(r3, 0.f); }
    if (ACT == 2) { r0 = tanhf(r0); r1 = tanhf(r1); r2 = tanhf(r2); r3 = tanhf(r3); }
    float4 out4 = {r0, r1, r2, r3};
    *reinterpret_cast<float4*>(C + (rowbase + tm * TM + i) * BN + tn * 4) = out4;
  }
}

// ---------------- GCN aggregation over pre-scaled hs ----------------
__global__ __launch_bounds__(256) void aggregate_kernel(const float* __restrict__ hs, const float* __restrict__ dis,
                                                        const int* __restrict__ offs, const int* __restrict__ ssrc,
                                                        const float* __restrict__ bias, float* __restrict__ outh,
                                                        int relu) {
  const int lane = threadIdx.x & 63;
  const int node = blockIdx.x * 4 + (threadIdx.x >> 6);
  const int half = lane >> 5;
  const int fl = (lane & 31) * 4;
  const int e0 = offs[node], e1 = offs[node + 1];
  float4 acc = {0.f, 0.f, 0.f, 0.f};
  int e = e0;
  for (; e + 8 <= e1; e += 8) {
    int s0 = ssrc[e + half];
    int s1 = ssrc[e + 2 + half];
    int s2 = ssrc[e + 4 + half];
    int s3 = ssrc[e + 6 + half];
    float4 v0 = *reinterpret_cast<const float4*>(hs + (size_t)s0 * 128 + fl);
    float4 v1 = *reinterpret_cast<const float4*>(hs + (size_t)s1 * 128 + fl);
    float4 v2 = *reinterpret_cast<const float4*>(hs + (size_t)s2 * 128 + fl);
    float4 v3 = *reinterpret_cast<const float4*>(hs + (size_t)s3 * 128 + fl);
    acc.x += v0.x + v1.x + v2.x + v3.x;
    acc.y += v0.y + v1.y + v2.y + v3.y;
    acc.z += v0.z + v1.z + v2.z + v3.z;
    acc.w += v0.w + v1.w + v2.w + v3.w;
  }
  for (; e < e1; e += 2) {
    int idx = e + half;
    bool valid = idx < e1;
    int s = valid ? ssrc[idx] : node;
    float4 v = *reinterpret_cast<const float4*>(hs + (size_t)s * 128 + fl);
    if (valid) { acc.x += v.x; acc.y += v.y; acc.z += v.z; acc.w += v.w; }
  }
  acc.x += __shfl_xor(acc.x, 32, 64);
  acc.y += __shfl_xor(acc.y, 32, 64);
  acc.z += __shfl_xor(acc.z, 32, 64);
  acc.w += __shfl_xor(acc.w, 32, 64);
  if (half == 0) {
    float dn = dis[node];
    float4 self = *reinterpret_cast<const float4*>(hs + (size_t)node * 128 + fl);
    float4 bv = *reinterpret_cast<const float4*>(bias + fl);
    float r0 = fmaf(acc.x + self.x, dn, bv.x);
    float r1 = fmaf(acc.y + self.y, dn, bv.y);
    float r2 = fmaf(acc.z + self.z, dn, bv.z);
    float r3 = fmaf(acc.w + self.w, dn, bv.w);
    if (relu) { r0 = fmaxf(r0, 0.f); r1 = fmaxf(r1, 0.f); r2 = fmaxf(r2, 0.f); r3 = fmaxf(r3, 0.f); }
    float4 r = {r0, r1, r2, r3};
    *reinterpret_cast<float4*>(outh + (size_t)node * 128 + fl) = r;
  }
}

// ---------------- double softmax over K=64 + per-node den write ----------------
__global__ __launch_bounds__(256) void softmax_kernel(float* __restrict__ s, const int* __restrict__ outdeg,
                                                      float* __restrict__ dn) {
  const int lane = threadIdx.x & 63;
  const int node = blockIdx.x * 4 + (threadIdx.x >> 6);
  float v = s[(size_t)node * KCL + lane];
  float m = wave_max(v);
  float e = __expf(v - m);
  float s1 = e / wave_sum(e);
  float m2 = wave_max(s1);
  float e2 = __expf(s1 - m2);
  float sd = e2 / wave_sum(e2);
  s[(size_t)node * KCL + lane] = sd;
  float q = wave_sum(sd * sd);
  if (lane == 0) dn[node] = q * (float)outdeg[node];
}

// ---------------- G[m] = sum_{src->m} s_d[src] ----------------
__global__ __launch_bounds__(256) void gather_kernel(const float* __restrict__ sd, const int* __restrict__ offs,
                                                     const int* __restrict__ ssrc, float* __restrict__ G) {
  const int lane = threadIdx.x & 63;
  const int node = blockIdx.x * 4 + (threadIdx.x >> 6);
  const int q = lane >> 4;
  const int fl = (lane & 15) * 4;
  const int e0 = offs[node], e1 = offs[node + 1];
  float4 acc = {0.f, 0.f, 0.f, 0.f};
  int e = e0;
  for (; e + 8 <= e1; e += 8) {
    int s0 = ssrc[e + q];
    int s1 = ssrc[e + 4 + q];
    float4 v0 = *reinterpret_cast<const float4*>(sd + (size_t)s0 * 64 + fl);
    float4 v1 = *reinterpret_cast<const float4*>(sd + (size_t)s1 * 64 + fl);
    acc.x += v0.x + v1.x;
    acc.y += v0.y + v1.y;
    acc.z += v0.z + v1.z;
    acc.w += v0.w + v1.w;
  }
  for (; e < e1; e += 4) {
    int idx = e + q;
    bool valid = idx < e1;
    int s = valid ? ssrc[idx] : node;
    float4 v = *reinterpret_cast<const float4*>(sd + (size_t)s * 64 + fl);
    if (valid) { acc.x += v.x; acc.y += v.y; acc.z += v.z; acc.w += v.w; }
  }
#pragma unroll
  for (int off = 16; off <= 32; off <<= 1) {
    acc.x += __shfl_xor(acc.x, off, 64);
    acc.y += __shfl_xor(acc.y, off, 64);
    acc.z += __shfl_xor(acc.z, off, 64);
    acc.w += __shfl_xor(acc.w, off, 64);
  }
  if (q == 0) {
    *reinterpret_cast<float4*>(G + (size_t)node * 64 + fl) = acc;
  }
}

// ---------------- fused rank reduction: C[64 x 256] = s_chunk^T [G | s | h2] ----------------
__global__ __launch_bounds__(512) void fused_atb_kernel(const float* __restrict__ sd, const float* __restrict__ G,
                                                        const float* __restrict__ h2, float* __restrict__ pF) {
  __shared__ float Xs[32][64];
  __shared__ float Ys[32][256];
  const int t = threadIdx.x;
  const int g = blockIdx.x >> 5, chunk = blockIdx.x & 31;
  const int n0 = g * 4096 + chunk * 128;
  const int rg = t >> 6;
  const int cl = t & 63;
  float acc[8][4];
#pragma unroll
  for (int r = 0; r < 8; r++)
#pragma unroll
    for (int j = 0; j < 4; j++) acc[r][j] = 0.f;

  for (int kt = 0; kt < 4; ++kt) {
    const int nb = n0 + kt * 32;
    {
      int k = t >> 4, c = (t & 15) * 4;
      *reinterpret_cast<float4*>(&Xs[k][c]) =
          *reinterpret_cast<const float4*>(&sd[(size_t)(nb + k) * 64 + c]);
    }
#pragma unroll
    for (int it = 0; it < 4; ++it) {
      int slot = it * 512 + t;
      int k = slot >> 6, c = (slot & 63) * 4;
      const float* srcp;
      if (c < 64)       srcp = &G[(size_t)(nb + k) * 64 + c];
      else if (c < 128) srcp = &sd[(size_t)(nb + k) * 64 + (c - 64)];
      else              srcp = &h2[(size_t)(nb + k) * 128 + (c - 128)];
      *reinterpret_cast<float4*>(&Ys[k][c]) = *reinterpret_cast<const float4*>(srcp);
    }
    __syncthreads();
#pragma unroll
    for (int k = 0; k < 32; ++k) {
      float4 b4 = *reinterpret_cast<const float4*>(&Ys[k][cl * 4]);
      float4 a0 = *reinterpret_cast<const float4*>(&Xs[k][rg * 8]);
      float4 a1 = *reinterpret_cast<const float4*>(&Xs[k][rg * 8 + 4]);
      float a[8] = {a0.x, a0.y, a0.z, a0.w, a1.x, a1.y, a1.z, a1.w};
#pragma unroll
      for (int r = 0; r < 8; r++) {
        acc[r][0] = fmaf(a[r], b4.x, acc[r][0]);
        acc[r][1] = fmaf(a[r], b4.y, acc[r][1]);
        acc[r][2] = fmaf(a[r], b4.z, acc[r][2]);
        acc[r][3] = fmaf(a[r], b4.w, acc[r][3]);
      }
    }
    __syncthreads();
  }
  float* dst = pF + (size_t)blockIdx.x * 16384;
#pragma unroll
  for (int r = 0; r < 8; r++) {
    float4 o4 = {acc[r][0], acc[r][1], acc[r][2], acc[r][3]};
    *reinterpret_cast<float4*>(&dst[(rg * 8 + r) * 256 + cl * 4]) = o4;
  }
}

// ---------------- merge 32 partials/graph -> oadj, ssb, outp ----------------
__global__ __launch_bounds__(256) void merge_kernel(const float* __restrict__ pF, float* __restrict__ oadj,
                                                    float* __restrict__ ssb, float* __restrict__ outp) {
  int idx = blockIdx.x * 256 + threadIdx.x;
  int g = idx >> 12, o4 = idx & 4095;
  float sx = 0.f, sy = 0.f, sz = 0.f, sw = 0.f;
#pragma unroll
  for (int q = 0; q < 32; ++q) {
    float4 v = *reinterpret_cast<const float4*>(pF + (size_t)(g * 32 + q) * 16384 + o4 * 4);
    sx += v.x; sy += v.y; sz += v.z; sw += v.w;
  }
  int row = o4 >> 6;
  int c = (o4 & 63) * 4;
  float4 o = {sx, sy, sz, sw};
  if (c < 64)
    *reinterpret_cast<float4*>(&oadj[g * 4096 + row * 64 + c]) = o;
  else if (c < 128)
    *reinterpret_cast<float4*>(&ssb[g * 4096 + row * 64 + (c - 64)]) = o;
  else
    *reinterpret_cast<float4*>(&outp[g * 8192 + row * 128 + (c - 128)]) = o;
}

// ---------------- losses + adjacency normalization + pooled_batch ----------------
__global__ __launch_bounds__(256) void epilogue_kernel(const float* __restrict__ oadj, const float* __restrict__ ssb,
                                                       const float* __restrict__ dn, float* __restrict__ out) {
  const int b = blockIdx.x, t = threadIdx.x;
  const float* A = oadj + b * 4096;
  const float* S = ssb + b * 4096;
  float da = 0.f;
#pragma unroll
  for (int i = 0; i < 16; i++) da += dn[b * 4096 + i * 256 + t];
  float dws = wave_sum(da);
  __shared__ float dw[4];
  if ((t & 63) == 0) dw[t >> 6] = dws;

  const int row = t >> 2, p = t & 3;
  float rs = 0.f, tra = 0.f, trs = 0.f, ssq = 0.f;
#pragma unroll
  for (int c = 0; c < 16; c++) {
    int j = p * 16 + c;
    float v = A[row * 64 + j];
    float w = S[row * 64 + j];
    ssq += w * w;
    if (j == row) { tra += v; trs += w; }
    else rs += v;
  }
  __shared__ float red[256];
  __shared__ float rowsum[64];
  red[t] = rs;
  __syncthreads();
  if (p == 0) rowsum[row] = red[t] + red[t + 1] + red[t + 2] + red[t + 3];
  float v1 = wave_sum(tra), v2 = wave_sum(trs), v3 = wave_sum(ssq);
  __shared__ float w1[4], w2[4], w3[4];
  if ((t & 63) == 0) { int w = t >> 6; w1[w] = v1; w2[w] = v2; w3[w] = v3; }
  __syncthreads();
  if (t == 0) {
    float TRA = w1[0] + w1[1] + w1[2] + w1[3];
    float TRS = w2[0] + w2[1] + w2[2] + w2[3];
    float SSQ = w3[0] + w3[1] + w3[2] + w3[3];
    float DEN = dw[0] + dw[1] + dw[2] + dw[3];
    atomicAdd(&out[98816], -(TRA / DEN) * 0.125f);
    float ssn = sqrtf(SSQ);
    atomicAdd(&out[98817], sqrtf(2.0f - TRS / (4.0f * ssn)) * 0.125f);
  }
  float di = sqrtf(rowsum[row]) + 1e-15f;
#pragma unroll
  for (int c = 0; c < 16; c++) {
    int j = p * 16 + c;
    float v = (j == row) ? 0.f : A[row * 64 + j];
    float dj = sqrtf(rowsum[j]) + 1e-15f;
    out[65536 + b * 4096 + row * 64 + j] = v / (di * dj);
  }
  if (t < 64) out[98304 + b * 64 + t] = (float)b;
}

extern "C" void kernel_launch(void* const* d_in, const int* in_sizes, int n_in,
                              void* d_out, int out_size, void* d_ws, size_t ws_size,
                              hipStream_t stream) {
  const float* x   = (const float*)d_in[0];
  const int*   ei  = (const int*)d_in[1];
  const float* W1  = (const float*)d_in[3];
  const float* b1  = (const float*)d_in[4];
  const float* W2  = (const float*)d_in[5];
  const float* b2  = (const float*)d_in[6];
  const float* Wa1 = (const float*)d_in[7];
  const float* ba1 = (const float*)d_in[8];
  const float* Wa2 = (const float*)d_in[9];
  const float* ba2 = (const float*)d_in[10];
  const float* Wo  = (const float*)d_in[11];
  const float* bo  = (const float*)d_in[12];
  const int* src = ei;
  const int* dst = ei + NEDGES;
  float* out = (float*)d_out;

  char* ws = (char*)d_ws;
  size_t o = 0;
  auto alloc = [&](size_t bytes) -> void* {
    void* p = ws + o;
    o += (bytes + 255) & ~(size_t)255;
    return p;
  };
  float* bufA  = (float*)alloc((size_t)NNODES * 128 * 4);  // 16 MB (reused as pF)
  float* bufB  = (float*)alloc((size_t)NNODES * 128 * 4);  // 16 MB
  float* sbuf  = (float*)alloc((size_t)NNODES * 64 * 4);   // 8 MB
  float* Gbuf  = (float*)alloc((size_t)NNODES * 64 * 4);   // 8 MB
  float* dis   = (float*)alloc((size_t)NNODES * 4);
  int* outdeg  = (int*)alloc((size_t)NNODES * 4);
  int* offs    = (int*)alloc((size_t)(NNODES + 1) * 4);
  int* ssrc    = (int*)alloc((size_t)NEDGES * 4);
  int* pIn     = (int*)alloc((size_t)8 * CPG * 4096 * 4);  // 2 MB
  int* pOut    = (int*)alloc((size_t)8 * CPG * 4096 * 4);  // 2 MB
  int* cbase   = (int*)alloc((size_t)8 * CPG * 4096 * 4);  // 2 MB
  float* dn    = (float*)alloc((size_t)NNODES * 4);
  float* oadj  = (float*)alloc(8 * 4096 * 4);
  float* ssb   = (float*)alloc(8 * 4096 * 4);
  float* outp  = (float*)alloc(8 * 8192 * 4);
  float* pF    = bufA;  // aliases bufA (dead by then)

  hipMemsetAsync(d_out, 0, (size_t)out_size * 4, stream);

  hist2_kernel<<<8 * CPG, 256, 0, stream>>>(src, dst, pIn, pOut);
  scan2_kernel<<<8, 1024, 0, stream>>>(pIn, pOut, offs, cbase, outdeg, dis);
  scatter2_kernel<<<8 * CPG, 256, 0, stream>>>(src, dst, cbase, ssrc);

  // GCN layer 1: hs = dis .* (x @ W1); h1 = relu(dis_n*(sum hs + hs_n) + b1)
  gemm_kernel<128, 0, 0, 1><<<NNODES / 64, 256, 0, stream>>>(x, W1, nullptr, dis, bufA);
  aggregate_kernel<<<NNODES / 4, 256, 0, stream>>>(bufA, dis, offs, ssrc, b1, bufB, 1);
  // GCN layer 2
  gemm_kernel<128, 0, 0, 1><<<NNODES / 64, 256, 0, stream>>>(bufB, W2, nullptr, dis, bufA);
  aggregate_kernel<<<NNODES / 4, 256, 0, stream>>>(bufA, dis, offs, ssrc, b2, bufB, 0);

  // assignment MLP
  gemm_kernel<128, 2, 1, 0><<<NNODES / 64, 256, 0, stream>>>(bufB, Wa1, ba1, nullptr, bufA);
  gemm_kernel<64, 0, 1, 0><<<NNODES / 64, 256, 0, stream>>>(bufA, Wa2, ba2, nullptr, sbuf);
  softmax_kernel<<<NNODES / 4, 256, 0, stream>>>(sbuf, outdeg, dn);

  gather_kernel<<<NNODES / 4, 256, 0, stream>>>(sbuf, offs, ssrc, Gbuf);
  fused_atb_kernel<<<256, 512, 0, stream>>>(sbuf, Gbuf, bufB, pF);
  merge_kernel<<<128, 256, 0, stream>>>(pF, oadj, ssb, outp);

  gemm_kernel<128, 1, 1, 0><<<512 / 64, 256, 0, stream>>>(outp, Wo, bo, nullptr, out);
  epilogue_kernel<<<8, 256, 0, stream>>>(oadj, ssb, dn, out);
}

// Round 6
// 285.145 us; speedup vs baseline: 2.3853x; 1.0987x over previous
//
#include <hip/hip_runtime.h>

#define NNODES 32768
#define NEDGES 524288
#define KCL 64
#define CPG 16   // histogram chunks per graph (4096 edges each)

typedef _Float16 half8v __attribute__((ext_vector_type(8)));
typedef _Float16 half4v __attribute__((ext_vector_type(4)));
typedef float floatx4 __attribute__((ext_vector_type(4)));

__device__ __forceinline__ float wave_sum(float v) {
#pragma unroll
  for (int off = 32; off > 0; off >>= 1) v += __shfl_xor(v, off, 64);
  return v;
}

__device__ __forceinline__ float wave_max(float v) {
#pragma unroll
  for (int off = 32; off > 0; off >>= 1) v = fmaxf(v, __shfl_xor(v, off, 64));
  return v;
}

// ---------------- per-chunk LDS histograms (no global atomics) ----------------
__global__ __launch_bounds__(256) void hist2_kernel(const int* __restrict__ src, const int* __restrict__ dst,
                                                    int* __restrict__ pIn, int* __restrict__ pOut) {
  __shared__ int hIn[4096];
  __shared__ int hOut[4096];
  const int t = threadIdx.x;
  const int g = blockIdx.x >> 4;
  const int ebase = (g << 16) + ((blockIdx.x & 15) << 12);
  const int nbase = g << 12;
  for (int i = t; i < 4096; i += 256) { hIn[i] = 0; hOut[i] = 0; }
  __syncthreads();
#pragma unroll
  for (int i = 0; i < 16; ++i) {
    int e = ebase + i * 256 + t;
    atomicAdd(&hIn[dst[e] - nbase], 1);
    atomicAdd(&hOut[src[e] - nbase], 1);
  }
  __syncthreads();
  int* dIn = pIn + ((size_t)blockIdx.x << 12);
  int* dOut = pOut + ((size_t)blockIdx.x << 12);
  for (int i = t; i < 4096; i += 256) { dIn[i] = hIn[i]; dOut[i] = hOut[i]; }
}

// ---------------- per-graph scan: offs, dis, outdeg, per-chunk cursor bases ----------------
__global__ __launch_bounds__(1024) void scan2_kernel(const int* __restrict__ pIn, const int* __restrict__ pOut,
                                                     int* __restrict__ offs, int* __restrict__ cbase,
                                                     int* __restrict__ outdeg, float* __restrict__ dis) {
  __shared__ int part[1024];
  const int t = threadIdx.x;
  const int g = blockIdx.x;
  int tot[4];
  int s = 0;
#pragma unroll
  for (int j = 0; j < 4; ++j) {
    int l = t * 4 + j;
    int cnt = 0;
#pragma unroll
    for (int c = 0; c < CPG; ++c) cnt += pIn[(((size_t)(g * CPG + c)) << 12) + l];
    tot[j] = cnt;
    s += cnt;
  }
  part[t] = s;
  __syncthreads();
  for (int off = 1; off < 1024; off <<= 1) {
    int add = (t >= off) ? part[t - off] : 0;
    __syncthreads();
    part[t] += add;
    __syncthreads();
  }
  int run = (g << 16) + ((t == 0) ? 0 : part[t - 1]);
#pragma unroll
  for (int j = 0; j < 4; ++j) {
    int l = t * 4 + j;
    int n = (g << 12) + l;
    offs[n] = run;
    dis[n] = rsqrtf((float)tot[j] + 1.0f);
    int od = 0;
#pragma unroll
    for (int c = 0; c < CPG; ++c) od += pOut[(((size_t)(g * CPG + c)) << 12) + l];
    outdeg[n] = od;
    int running = run;
#pragma unroll
    for (int c = 0; c < CPG; ++c) {
      size_t idx = (((size_t)(g * CPG + c)) << 12) + l;
      cbase[idx] = running;
      running += pIn[idx];
    }
    run += tot[j];
  }
  if (g == 0 && t == 0) offs[NNODES] = NEDGES;
}

// ---------------- scatter via LDS cursors (no global atomics) ----------------
__global__ __launch_bounds__(256) void scatter2_kernel(const int* __restrict__ src, const int* __restrict__ dst,
                                                       const int* __restrict__ cbase, int* __restrict__ ssrc) {
  __shared__ int cur[4096];
  const int t = threadIdx.x;
  const int g = blockIdx.x >> 4;
  const int ebase = (g << 16) + ((blockIdx.x & 15) << 12);
  const int nbase = g << 12;
  const int* cb = cbase + ((size_t)blockIdx.x << 12);
  for (int i = t; i < 4096; i += 256) cur[i] = cb[i];
  __syncthreads();
#pragma unroll
  for (int i = 0; i < 16; ++i) {
    int e = ebase + i * 256 + t;
    int d = dst[e] - nbase;
    int pos = atomicAdd(&cur[d], 1);
    ssrc[pos] = src[e];
  }
}

// ---------------- fp32 -> fp16 convert ----------------
__global__ __launch_bounds__(256) void cvt_kernel(const float* __restrict__ in, _Float16* __restrict__ outv) {
  size_t i = (size_t)blockIdx.x * 256 + threadIdx.x;
  float4 v = *reinterpret_cast<const float4*>(in + i * 4);
  half4v h = {(_Float16)v.x, (_Float16)v.y, (_Float16)v.z, (_Float16)v.w};
  *reinterpret_cast<half4v*>(outv + i * 4) = h;
}

// ---------------- MFMA fp16 GEMM: C[M x BN] = A[M x 128] @ W[128 x BN] ----------------
// block 256 (4 waves), 128 rows/block; wave = 32 rows x BN cols. W^T staged in LDS (fp16).
// A-frag layout: A[m=lane&15][k=quad*8+j]; B-frag: B[k=quad*8+j][n=lane&15];
// C/D: col=lane&15, row=quad*4+reg.
template <int BN, int ACT, int BIAS, int SCALE, int OUTH>
__global__ __launch_bounds__(256) void mgemm_kernel(const _Float16* __restrict__ A, const float* __restrict__ W,
                                                    const float* __restrict__ bias, const float* __restrict__ rowscale,
                                                    void* __restrict__ Cout) {
  constexpr int CT = BN / 16;
  __shared__ _Float16 WT[BN][136];
  const int t = threadIdx.x;
  for (int i = t; i < 128 * BN; i += 256) {
    int k = i / BN, n = i % BN;
    WT[n][k] = (_Float16)W[i];
  }
  __syncthreads();
  const int lane = t & 63;
  const int quad = lane >> 4, l16 = lane & 15;
  const long rowbase = (long)blockIdx.x * 128 + (t >> 6) * 32;
  half8v af[2][4];
#pragma unroll
  for (int rt = 0; rt < 2; rt++)
#pragma unroll
    for (int kt = 0; kt < 4; kt++)
      af[rt][kt] = *reinterpret_cast<const half8v*>(A + (rowbase + rt * 16 + l16) * 128 + kt * 32 + quad * 8);
  floatx4 acc[2][CT];
#pragma unroll
  for (int rt = 0; rt < 2; rt++)
#pragma unroll
    for (int ct = 0; ct < CT; ct++) acc[rt][ct] = {0.f, 0.f, 0.f, 0.f};
#pragma unroll
  for (int kt = 0; kt < 4; kt++) {
    half8v bf[CT];
#pragma unroll
    for (int ct = 0; ct < CT; ct++)
      bf[ct] = *reinterpret_cast<const half8v*>(&WT[ct * 16 + l16][kt * 32 + quad * 8]);
#pragma unroll
    for (int rt = 0; rt < 2; rt++)
#pragma unroll
      for (int ct = 0; ct < CT; ct++)
        acc[rt][ct] = __builtin_amdgcn_mfma_f32_16x16x32_f16(af[rt][kt], bf[ct], acc[rt][ct], 0, 0, 0);
  }
#pragma unroll
  for (int rt = 0; rt < 2; rt++) {
#pragma unroll
    for (int r = 0; r < 4; r++) {
      long row = rowbase + rt * 16 + quad * 4 + r;
      float sc = SCALE ? rowscale[row] : 1.f;
#pragma unroll
      for (int ct = 0; ct < CT; ct++) {
        float v = acc[rt][ct][r];
        if (SCALE) v *= sc;
        if (BIAS) v += bias[ct * 16 + l16];
        if (ACT == 1) v = fmaxf(v, 0.f);
        if (ACT == 2) v = tanhf(v);
        if (OUTH) ((_Float16*)Cout)[row * BN + ct * 16 + l16] = (_Float16)v;
        else ((float*)Cout)[row * BN + ct * 16 + l16] = v;
      }
    }
  }
}

// ---------------- fp32 GEMM (final small one): C[M x 128] = A @ Wo + bias, relu ----------------
__global__ __launch_bounds__(256) void gemm_kernel(const float* __restrict__ A, const float* __restrict__ W,
                                                   const float* __restrict__ bias, float* __restrict__ C) {
  __shared__ float As[32][68];
  __shared__ float Ws[32][128];
  const int t = threadIdx.x;
  const int tn = t % 32;
  const int tm = t / 32;
  const long rowbase = (long)blockIdx.x * 64;
  float acc[8][4];
#pragma unroll
  for (int i = 0; i < 8; i++)
#pragma unroll
    for (int j = 0; j < 4; j++) acc[i][j] = 0.f;
  for (int k0 = 0; k0 < 128; k0 += 32) {
#pragma unroll
    for (int it = 0; it < 2; it++) {
      int lin = t + it * 256;
      int row = lin >> 3, c4 = lin & 7;
      float4 v = *reinterpret_cast<const float4*>(A + (rowbase + row) * 128 + k0 + c4 * 4);
      As[c4 * 4 + 0][row] = v.x;
      As[c4 * 4 + 1][row] = v.y;
      As[c4 * 4 + 2][row] = v.z;
      As[c4 * 4 + 3][row] = v.w;
    }
#pragma unroll
    for (int it = 0; it < 4; it++) {
      int lin = t + it * 256;
      int row = lin / 32, c4 = lin % 32;
      *reinterpret_cast<float4*>(&Ws[row][c4 * 4]) =
          *reinterpret_cast<const float4*>(W + (size_t)(k0 + row) * 128 + c4 * 4);
    }
    __syncthreads();
#pragma unroll
    for (int k = 0; k < 32; k++) {
      float4 wv = *reinterpret_cast<const float4*>(&Ws[k][tn * 4]);
      float a[8];
#pragma unroll
      for (int i = 0; i < 8; i += 4) {
        float4 av = *reinterpret_cast<const float4*>(&As[k][tm * 8 + i]);
        a[i] = av.x; a[i + 1] = av.y; a[i + 2] = av.z; a[i + 3] = av.w;
      }
#pragma unroll
      for (int i = 0; i < 8; i++) {
        acc[i][0] = fmaf(a[i], wv.x, acc[i][0]);
        acc[i][1] = fmaf(a[i], wv.y, acc[i][1]);
        acc[i][2] = fmaf(a[i], wv.z, acc[i][2]);
        acc[i][3] = fmaf(a[i], wv.w, acc[i][3]);
      }
    }
    __syncthreads();
  }
  float4 bv = *reinterpret_cast<const float4*>(bias + tn * 4);
#pragma unroll
  for (int i = 0; i < 8; i++) {
    float r0 = fmaxf(acc[i][0] + bv.x, 0.f);
    float r1 = fmaxf(acc[i][1] + bv.y, 0.f);
    float r2 = fmaxf(acc[i][2] + bv.z, 0.f);
    float r3 = fmaxf(acc[i][3] + bv.w, 0.f);
    float4 out4 = {r0, r1, r2, r3};
    *reinterpret_cast<float4*>(C + (rowbase + tm * 8 + i) * 128 + tn * 4) = out4;
  }
}

// ---------------- GCN aggregation over fp16 pre-scaled hs ----------------
// out[n] = dis[n]*(sum_{src->n} hs[src] + hs[n]) + b ; wave/node, 4 edges per half8 load.
__global__ __launch_bounds__(256) void aggregate_kernel(const _Float16* __restrict__ hs, const float* __restrict__ dis,
                                                        const int* __restrict__ offs, const int* __restrict__ ssrc,
                                                        const float* __restrict__ bias, _Float16* __restrict__ outh,
                                                        int relu) {
  const int lane = threadIdx.x & 63;
  const int node = blockIdx.x * 4 + (threadIdx.x >> 6);
  const int q = lane >> 4;
  const int fl = (lane & 15) * 8;
  const int e0 = offs[node], e1 = offs[node + 1];
  float fa[8];
#pragma unroll
  for (int j = 0; j < 8; j++) fa[j] = 0.f;
  int e = e0;
  for (; e + 8 <= e1; e += 8) {
    int s0 = ssrc[e + q];
    int s1 = ssrc[e + 4 + q];
    half8v v0 = *reinterpret_cast<const half8v*>(hs + (size_t)s0 * 128 + fl);
    half8v v1 = *reinterpret_cast<const half8v*>(hs + (size_t)s1 * 128 + fl);
#pragma unroll
    for (int j = 0; j < 8; j++) fa[j] += (float)v0[j] + (float)v1[j];
  }
  for (; e < e1; e += 4) {
    int idx = e + q;
    bool valid = idx < e1;
    int s = valid ? ssrc[idx] : node;
    half8v v = *reinterpret_cast<const half8v*>(hs + (size_t)s * 128 + fl);
    if (valid) {
#pragma unroll
      for (int j = 0; j < 8; j++) fa[j] += (float)v[j];
    }
  }
#pragma unroll
  for (int j = 0; j < 8; j++) {
    fa[j] += __shfl_xor(fa[j], 16, 64);
    fa[j] += __shfl_xor(fa[j], 32, 64);
  }
  if (q == 0) {
    float dn = dis[node];
    half8v self = *reinterpret_cast<const half8v*>(hs + (size_t)node * 128 + fl);
    float4 b0 = *reinterpret_cast<const float4*>(bias + fl);
    float4 b1 = *reinterpret_cast<const float4*>(bias + fl + 4);
    float bb[8] = {b0.x, b0.y, b0.z, b0.w, b1.x, b1.y, b1.z, b1.w};
    half8v r;
#pragma unroll
    for (int j = 0; j < 8; j++) {
      float v = fmaf(fa[j] + (float)self[j], dn, bb[j]);
      if (relu) v = fmaxf(v, 0.f);
      r[j] = (_Float16)v;
    }
    *reinterpret_cast<half8v*>(outh + (size_t)node * 128 + fl) = r;
  }
}

// ---------------- double softmax over K=64 + per-node den write ----------------
__global__ __launch_bounds__(256) void softmax_kernel(float* __restrict__ s, const int* __restrict__ outdeg,
                                                      float* __restrict__ dn) {
  const int lane = threadIdx.x & 63;
  const int node = blockIdx.x * 4 + (threadIdx.x >> 6);
  float v = s[(size_t)node * KCL + lane];
  float m = wave_max(v);
  float e = __expf(v - m);
  float s1 = e / wave_sum(e);
  float m2 = wave_max(s1);
  float e2 = __expf(s1 - m2);
  float sd = e2 / wave_sum(e2);
  s[(size_t)node * KCL + lane] = sd;
  float q = wave_sum(sd * sd);
  if (lane == 0) dn[node] = q * (float)outdeg[node];
}

// ---------------- G[m] = sum_{src->m} s_d[src] ----------------
__global__ __launch_bounds__(256) void gather_kernel(const float* __restrict__ sd, const int* __restrict__ offs,
                                                     const int* __restrict__ ssrc, float* __restrict__ G) {
  const int lane = threadIdx.x & 63;
  const int node = blockIdx.x * 4 + (threadIdx.x >> 6);
  const int q = lane >> 4;
  const int fl = (lane & 15) * 4;
  const int e0 = offs[node], e1 = offs[node + 1];
  float4 acc = {0.f, 0.f, 0.f, 0.f};
  int e = e0;
  for (; e + 8 <= e1; e += 8) {
    int s0 = ssrc[e + q];
    int s1 = ssrc[e + 4 + q];
    float4 v0 = *reinterpret_cast<const float4*>(sd + (size_t)s0 * 64 + fl);
    float4 v1 = *reinterpret_cast<const float4*>(sd + (size_t)s1 * 64 + fl);
    acc.x += v0.x + v1.x;
    acc.y += v0.y + v1.y;
    acc.z += v0.z + v1.z;
    acc.w += v0.w + v1.w;
  }
  for (; e < e1; e += 4) {
    int idx = e + q;
    bool valid = idx < e1;
    int s = valid ? ssrc[idx] : node;
    float4 v = *reinterpret_cast<const float4*>(sd + (size_t)s * 64 + fl);
    if (valid) { acc.x += v.x; acc.y += v.y; acc.z += v.z; acc.w += v.w; }
  }
#pragma unroll
  for (int off = 16; off <= 32; off <<= 1) {
    acc.x += __shfl_xor(acc.x, off, 64);
    acc.y += __shfl_xor(acc.y, off, 64);
    acc.z += __shfl_xor(acc.z, off, 64);
    acc.w += __shfl_xor(acc.w, off, 64);
  }
  if (q == 0) {
    *reinterpret_cast<float4*>(G + (size_t)node * 64 + fl) = acc;
  }
}

// ---------------- fused rank reduction: C[64 x 256] = s_chunk^T [G | s | h2] ----------------
__global__ __launch_bounds__(512) void fused_atb_kernel(const float* __restrict__ sd, const float* __restrict__ G,
                                                        const _Float16* __restrict__ h2, float* __restrict__ pF) {
  __shared__ float Xs[32][64];
  __shared__ float Ys[32][256];
  const int t = threadIdx.x;
  const int g = blockIdx.x >> 5, chunk = blockIdx.x & 31;
  const int n0 = g * 4096 + chunk * 128;
  const int rg = t >> 6;
  const int cl = t & 63;
  float acc[8][4];
#pragma unroll
  for (int r = 0; r < 8; r++)
#pragma unroll
    for (int j = 0; j < 4; j++) acc[r][j] = 0.f;

  for (int kt = 0; kt < 4; ++kt) {
    const int nb = n0 + kt * 32;
    {
      int k = t >> 4, c = (t & 15) * 4;
      *reinterpret_cast<float4*>(&Xs[k][c]) =
          *reinterpret_cast<const float4*>(&sd[(size_t)(nb + k) * 64 + c]);
    }
#pragma unroll
    for (int it = 0; it < 4; ++it) {
      int slot = it * 512 + t;
      int k = slot >> 6, c = (slot & 63) * 4;
      float4 val;
      if (c < 64) {
        val = *reinterpret_cast<const float4*>(&G[(size_t)(nb + k) * 64 + c]);
      } else if (c < 128) {
        val = *reinterpret_cast<const float4*>(&sd[(size_t)(nb + k) * 64 + (c - 64)]);
      } else {
        half4v hv = *reinterpret_cast<const half4v*>(&h2[(size_t)(nb + k) * 128 + (c - 128)]);
        val.x = (float)hv[0]; val.y = (float)hv[1]; val.z = (float)hv[2]; val.w = (float)hv[3];
      }
      *reinterpret_cast<float4*>(&Ys[k][c]) = val;
    }
    __syncthreads();
#pragma unroll
    for (int k = 0; k < 32; ++k) {
      float4 b4 = *reinterpret_cast<const float4*>(&Ys[k][cl * 4]);
      float4 a0 = *reinterpret_cast<const float4*>(&Xs[k][rg * 8]);
      float4 a1 = *reinterpret_cast<const float4*>(&Xs[k][rg * 8 + 4]);
      float a[8] = {a0.x, a0.y, a0.z, a0.w, a1.x, a1.y, a1.z, a1.w};
#pragma unroll
      for (int r = 0; r < 8; r++) {
        acc[r][0] = fmaf(a[r], b4.x, acc[r][0]);
        acc[r][1] = fmaf(a[r], b4.y, acc[r][1]);
        acc[r][2] = fmaf(a[r], b4.z, acc[r][2]);
        acc[r][3] = fmaf(a[r], b4.w, acc[r][3]);
      }
    }
    __syncthreads();
  }
  float* dst = pF + (size_t)blockIdx.x * 16384;
#pragma unroll
  for (int r = 0; r < 8; r++) {
    float4 o4 = {acc[r][0], acc[r][1], acc[r][2], acc[r][3]};
    *reinterpret_cast<float4*>(&dst[(rg * 8 + r) * 256 + cl * 4]) = o4;
  }
}

// ---------------- merge 32 partials/graph -> oadj, ssb, outp ----------------
__global__ __launch_bounds__(256) void merge_kernel(const float* __restrict__ pF, float* __restrict__ oadj,
                                                    float* __restrict__ ssb, float* __restrict__ outp) {
  int idx = blockIdx.x * 256 + threadIdx.x;
  int g = idx >> 12, o4 = idx & 4095;
  float sx = 0.f, sy = 0.f, sz = 0.f, sw = 0.f;
#pragma unroll
  for (int q = 0; q < 32; ++q) {
    float4 v = *reinterpret_cast<const float4*>(pF + (size_t)(g * 32 + q) * 16384 + o4 * 4);
    sx += v.x; sy += v.y; sz += v.z; sw += v.w;
  }
  int row = o4 >> 6;
  int c = (o4 & 63) * 4;
  float4 o = {sx, sy, sz, sw};
  if (c < 64)
    *reinterpret_cast<float4*>(&oadj[g * 4096 + row * 64 + c]) = o;
  else if (c < 128)
    *reinterpret_cast<float4*>(&ssb[g * 4096 + row * 64 + (c - 64)]) = o;
  else
    *reinterpret_cast<float4*>(&outp[g * 8192 + row * 128 + (c - 128)]) = o;
}

// ---------------- losses + adjacency normalization + pooled_batch ----------------
__global__ __launch_bounds__(256) void epilogue_kernel(const float* __restrict__ oadj, const float* __restrict__ ssb,
                                                       const float* __restrict__ dn, float* __restrict__ out) {
  const int b = blockIdx.x, t = threadIdx.x;
  const float* A = oadj + b * 4096;
  const float* S = ssb + b * 4096;
  float da = 0.f;
#pragma unroll
  for (int i = 0; i < 16; i++) da += dn[b * 4096 + i * 256 + t];
  float dws = wave_sum(da);
  __shared__ float dw[4];
  if ((t & 63) == 0) dw[t >> 6] = dws;

  const int row = t >> 2, p = t & 3;
  float rs = 0.f, tra = 0.f, trs = 0.f, ssq = 0.f;
#pragma unroll
  for (int c = 0; c < 16; c++) {
    int j = p * 16 + c;
    float v = A[row * 64 + j];
    float w = S[row * 64 + j];
    ssq += w * w;
    if (j == row) { tra += v; trs += w; }
    else rs += v;
  }
  __shared__ float red[256];
  __shared__ float rowsum[64];
  red[t] = rs;
  __syncthreads();
  if (p == 0) rowsum[row] = red[t] + red[t + 1] + red[t + 2] + red[t + 3];
  float v1 = wave_sum(tra), v2 = wave_sum(trs), v3 = wave_sum(ssq);
  __shared__ float w1[4], w2[4], w3[4];
  if ((t & 63) == 0) { int w = t >> 6; w1[w] = v1; w2[w] = v2; w3[w] = v3; }
  __syncthreads();
  if (t == 0) {
    float TRA = w1[0] + w1[1] + w1[2] + w1[3];
    float TRS = w2[0] + w2[1] + w2[2] + w2[3];
    float SSQ = w3[0] + w3[1] + w3[2] + w3[3];
    float DEN = dw[0] + dw[1] + dw[2] + dw[3];
    atomicAdd(&out[98816], -(TRA / DEN) * 0.125f);
    float ssn = sqrtf(SSQ);
    atomicAdd(&out[98817], sqrtf(2.0f - TRS / (4.0f * ssn)) * 0.125f);
  }
  float di = sqrtf(rowsum[row]) + 1e-15f;
#pragma unroll
  for (int c = 0; c < 16; c++) {
    int j = p * 16 + c;
    float v = (j == row) ? 0.f : A[row * 64 + j];
    float dj = sqrtf(rowsum[j]) + 1e-15f;
    out[65536 + b * 4096 + row * 64 + j] = v / (di * dj);
  }
  if (t < 64) out[98304 + b * 64 + t] = (float)b;
}

extern "C" void kernel_launch(void* const* d_in, const int* in_sizes, int n_in,
                              void* d_out, int out_size, void* d_ws, size_t ws_size,
                              hipStream_t stream) {
  const float* x   = (const float*)d_in[0];
  const int*   ei  = (const int*)d_in[1];
  const float* W1  = (const float*)d_in[3];
  const float* b1  = (const float*)d_in[4];
  const float* W2  = (const float*)d_in[5];
  const float* b2  = (const float*)d_in[6];
  const float* Wa1 = (const float*)d_in[7];
  const float* ba1 = (const float*)d_in[8];
  const float* Wa2 = (const float*)d_in[9];
  const float* ba2 = (const float*)d_in[10];
  const float* Wo  = (const float*)d_in[11];
  const float* bo  = (const float*)d_in[12];
  const int* src = ei;
  const int* dst = ei + NEDGES;
  float* out = (float*)d_out;

  char* ws = (char*)d_ws;
  size_t o = 0;
  auto alloc = [&](size_t bytes) -> void* {
    void* p = ws + o;
    o += (bytes + 255) & ~(size_t)255;
    return p;
  };
  _Float16* xh   = (_Float16*)alloc((size_t)NNODES * 128 * 2);  // 8 MB
  _Float16* h16A = (_Float16*)alloc((size_t)NNODES * 128 * 2);  // 8 MB
  _Float16* h16B = (_Float16*)alloc((size_t)NNODES * 128 * 2);  // 8 MB
  _Float16* h16C = (_Float16*)alloc((size_t)NNODES * 128 * 2);  // 8 MB (h2, persists)
  float* sbuf  = (float*)alloc((size_t)NNODES * 64 * 4);        // 8 MB
  float* Gbuf  = (float*)alloc((size_t)NNODES * 64 * 4);        // 8 MB
  float* pF    = (float*)alloc((size_t)256 * 16384 * 4);        // 16 MB
  float* dis   = (float*)alloc((size_t)NNODES * 4);
  int* outdeg  = (int*)alloc((size_t)NNODES * 4);
  int* offs    = (int*)alloc((size_t)(NNODES + 1) * 4);
  int* ssrc    = (int*)alloc((size_t)NEDGES * 4);
  int* pIn     = (int*)alloc((size_t)8 * CPG * 4096 * 4);
  int* pOut    = (int*)alloc((size_t)8 * CPG * 4096 * 4);
  int* cbase   = (int*)alloc((size_t)8 * CPG * 4096 * 4);
  float* dn    = (float*)alloc((size_t)NNODES * 4);
  float* oadj  = (float*)alloc(8 * 4096 * 4);
  float* ssb   = (float*)alloc(8 * 4096 * 4);
  float* outp  = (float*)alloc(8 * 8192 * 4);

  hipMemsetAsync(d_out, 0, (size_t)out_size * 4, stream);

  hist2_kernel<<<8 * CPG, 256, 0, stream>>>(src, dst, pIn, pOut);
  scan2_kernel<<<8, 1024, 0, stream>>>(pIn, pOut, offs, cbase, outdeg, dis);
  scatter2_kernel<<<8 * CPG, 256, 0, stream>>>(src, dst, cbase, ssrc);

  cvt_kernel<<<NNODES * 128 / 4 / 256, 256, 0, stream>>>(x, xh);

  // GCN layer 1: hs = dis .* (x @ W1) [fp16]; h1 = relu(dis_n*(sum hs + hs_n) + b1) [fp16]
  mgemm_kernel<128, 0, 0, 1, 1><<<NNODES / 128, 256, 0, stream>>>(xh, W1, nullptr, dis, h16A);
  aggregate_kernel<<<NNODES / 4, 256, 0, stream>>>(h16A, dis, offs, ssrc, b1, h16B, 1);
  // GCN layer 2: h2 [fp16]
  mgemm_kernel<128, 0, 0, 1, 1><<<NNODES / 128, 256, 0, stream>>>(h16B, W2, nullptr, dis, h16A);
  aggregate_kernel<<<NNODES / 4, 256, 0, stream>>>(h16A, dis, offs, ssrc, b2, h16C, 0);

  // assignment MLP: z = tanh(h2 @ Wa1 + ba1) [fp16]; logits = z @ Wa2 + ba2 [fp32]
  mgemm_kernel<128, 2, 1, 0, 1><<<NNODES / 128, 256, 0, stream>>>(h16C, Wa1, ba1, nullptr, h16A);
  mgemm_kernel<64, 0, 1, 0, 0><<<NNODES / 128, 256, 0, stream>>>(h16A, Wa2, ba2, nullptr, sbuf);
  softmax_kernel<<<NNODES / 4, 256, 0, stream>>>(sbuf, outdeg, dn);

  gather_kernel<<<NNODES / 4, 256, 0, stream>>>(sbuf, offs, ssrc, Gbuf);
  fused_atb_kernel<<<256, 512, 0, stream>>>(sbuf, Gbuf, h16C, pF);
  merge_kernel<<<128, 256, 0, stream>>>(pF, oadj, ssb, outp);

  gemm_kernel<<<8, 256, 0, stream>>>(outp, Wo, bo, out);
  epilogue_kernel<<<8, 256, 0, stream>>>(oadj, ssb, dn, out);
}

// Round 7
// 250.557 us; speedup vs baseline: 2.7145x; 1.1380x over previous
//
#include <hip/hip_runtime.h>

#define NNODES 32768
#define NEDGES 524288
#define KCL 64
#define CPG 16   // histogram chunks per graph (4096 edges each)

typedef _Float16 half8v __attribute__((ext_vector_type(8)));
typedef _Float16 half4v __attribute__((ext_vector_type(4)));
typedef float floatx4 __attribute__((ext_vector_type(4)));

__device__ __forceinline__ float wave_sum(float v) {
#pragma unroll
  for (int off = 32; off > 0; off >>= 1) v += __shfl_xor(v, off, 64);
  return v;
}

__device__ __forceinline__ float wave_max(float v) {
#pragma unroll
  for (int off = 32; off > 0; off >>= 1) v = fmaxf(v, __shfl_xor(v, off, 64));
  return v;
}

// ---------------- per-chunk LDS histograms (no global atomics) ----------------
__global__ __launch_bounds__(256) void hist2_kernel(const int* __restrict__ src, const int* __restrict__ dst,
                                                    int* __restrict__ pIn, int* __restrict__ pOut) {
  __shared__ int hIn[4096];
  __shared__ int hOut[4096];
  const int t = threadIdx.x;
  const int g = blockIdx.x >> 4;
  const int ebase = (g << 16) + ((blockIdx.x & 15) << 12);
  const int nbase = g << 12;
  for (int i = t; i < 4096; i += 256) { hIn[i] = 0; hOut[i] = 0; }
  __syncthreads();
#pragma unroll
  for (int i = 0; i < 16; ++i) {
    int e = ebase + i * 256 + t;
    atomicAdd(&hIn[dst[e] - nbase], 1);
    atomicAdd(&hOut[src[e] - nbase], 1);
  }
  __syncthreads();
  int* dIn = pIn + ((size_t)blockIdx.x << 12);
  int* dOut = pOut + ((size_t)blockIdx.x << 12);
  for (int i = t; i < 4096; i += 256) { dIn[i] = hIn[i]; dOut[i] = hOut[i]; }
}

// ---------------- per-graph scan: offs, dis, outdeg, per-chunk cursor bases ----------------
__global__ __launch_bounds__(1024) void scan2_kernel(const int* __restrict__ pIn, const int* __restrict__ pOut,
                                                     int* __restrict__ offs, int* __restrict__ cbase,
                                                     int* __restrict__ outdeg, float* __restrict__ dis) {
  __shared__ int part[1024];
  const int t = threadIdx.x;
  const int g = blockIdx.x;
  int tot[4];
  int s = 0;
#pragma unroll
  for (int j = 0; j < 4; ++j) {
    int l = t * 4 + j;
    int cnt = 0;
#pragma unroll
    for (int c = 0; c < CPG; ++c) cnt += pIn[(((size_t)(g * CPG + c)) << 12) + l];
    tot[j] = cnt;
    s += cnt;
  }
  part[t] = s;
  __syncthreads();
  for (int off = 1; off < 1024; off <<= 1) {
    int add = (t >= off) ? part[t - off] : 0;
    __syncthreads();
    part[t] += add;
    __syncthreads();
  }
  int run = (g << 16) + ((t == 0) ? 0 : part[t - 1]);
#pragma unroll
  for (int j = 0; j < 4; ++j) {
    int l = t * 4 + j;
    int n = (g << 12) + l;
    offs[n] = run;
    dis[n] = rsqrtf((float)tot[j] + 1.0f);
    int od = 0;
#pragma unroll
    for (int c = 0; c < CPG; ++c) od += pOut[(((size_t)(g * CPG + c)) << 12) + l];
    outdeg[n] = od;
    int running = run;
#pragma unroll
    for (int c = 0; c < CPG; ++c) {
      size_t idx = (((size_t)(g * CPG + c)) << 12) + l;
      cbase[idx] = running;
      running += pIn[idx];
    }
    run += tot[j];
  }
  if (g == 0 && t == 0) offs[NNODES] = NEDGES;
}

// ---------------- scatter via LDS cursors (no global atomics) ----------------
__global__ __launch_bounds__(256) void scatter2_kernel(const int* __restrict__ src, const int* __restrict__ dst,
                                                       const int* __restrict__ cbase, int* __restrict__ ssrc) {
  __shared__ int cur[4096];
  const int t = threadIdx.x;
  const int g = blockIdx.x >> 4;
  const int ebase = (g << 16) + ((blockIdx.x & 15) << 12);
  const int nbase = g << 12;
  const int* cb = cbase + ((size_t)blockIdx.x << 12);
  for (int i = t; i < 4096; i += 256) cur[i] = cb[i];
  __syncthreads();
#pragma unroll
  for (int i = 0; i < 16; ++i) {
    int e = ebase + i * 256 + t;
    int d = dst[e] - nbase;
    int pos = atomicAdd(&cur[d], 1);
    ssrc[pos] = src[e];
  }
}

// ---------------- MFMA fp16 GEMM: C[M x BN] = A[M x 128] @ W[128 x BN] ----------------
// block 256 (4 waves), 128 rows/block, XCD-swizzled: g=blockIdx&7, j=blockIdx>>3.
// A-frag: A[m=lane&15][k=quad*8+j]; C/D: col=lane&15, row=quad*4+reg.
// SMAX: fused double-softmax epilogue (BN=64) writing fp16 s_d + per-node den.
template <int BN, int ACT, int BIAS, int SCALE, int AFP32, int OUTH, int SMAX>
__global__ __launch_bounds__(256) void mgemm_kernel(const void* __restrict__ Ain, const float* __restrict__ W,
                                                    const float* __restrict__ bias, const float* __restrict__ rowscale,
                                                    const int* __restrict__ outdeg, float* __restrict__ dnp,
                                                    void* __restrict__ Cout) {
  constexpr int CT = BN / 16;
  __shared__ _Float16 WT[BN][136];
  const int t = threadIdx.x;
  for (int i = t; i < 128 * BN; i += 256) {
    int k = i / BN, n = i % BN;
    WT[n][k] = (_Float16)W[i];
  }
  __syncthreads();
  const int lane = t & 63;
  const int quad = lane >> 4, l16 = lane & 15;
  const long rowbase = (long)(blockIdx.x & 7) * 4096 + (long)(blockIdx.x >> 3) * 128 + (t >> 6) * 32;
  half8v af[2][4];
#pragma unroll
  for (int rt = 0; rt < 2; rt++)
#pragma unroll
    for (int kt = 0; kt < 4; kt++) {
      if (AFP32) {
        const float* A32 = (const float*)Ain;
        const float* p = A32 + (rowbase + rt * 16 + l16) * 128 + kt * 32 + quad * 8;
        float4 p0 = *reinterpret_cast<const float4*>(p);
        float4 p1 = *reinterpret_cast<const float4*>(p + 4);
        half8v h = {(_Float16)p0.x, (_Float16)p0.y, (_Float16)p0.z, (_Float16)p0.w,
                    (_Float16)p1.x, (_Float16)p1.y, (_Float16)p1.z, (_Float16)p1.w};
        af[rt][kt] = h;
      } else {
        const _Float16* A16 = (const _Float16*)Ain;
        af[rt][kt] = *reinterpret_cast<const half8v*>(A16 + (rowbase + rt * 16 + l16) * 128 + kt * 32 + quad * 8);
      }
    }
  floatx4 acc[2][CT];
#pragma unroll
  for (int rt = 0; rt < 2; rt++)
#pragma unroll
    for (int ct = 0; ct < CT; ct++) acc[rt][ct] = {0.f, 0.f, 0.f, 0.f};
#pragma unroll
  for (int kt = 0; kt < 4; kt++) {
    half8v bf[CT];
#pragma unroll
    for (int ct = 0; ct < CT; ct++)
      bf[ct] = *reinterpret_cast<const half8v*>(&WT[ct * 16 + l16][kt * 32 + quad * 8]);
#pragma unroll
    for (int rt = 0; rt < 2; rt++)
#pragma unroll
      for (int ct = 0; ct < CT; ct++)
        acc[rt][ct] = __builtin_amdgcn_mfma_f32_16x16x32_f16(af[rt][kt], bf[ct], acc[rt][ct], 0, 0, 0);
  }
#pragma unroll
  for (int rt = 0; rt < 2; rt++) {
#pragma unroll
    for (int r = 0; r < 4; r++) {
      long row = rowbase + rt * 16 + quad * 4 + r;
      if (SMAX) {
        float v[CT];
#pragma unroll
        for (int ct = 0; ct < CT; ct++) v[ct] = acc[rt][ct][r] + bias[ct * 16 + l16];
        float m = v[0];
#pragma unroll
        for (int ct = 1; ct < CT; ct++) m = fmaxf(m, v[ct]);
#pragma unroll
        for (int off = 1; off <= 8; off <<= 1) m = fmaxf(m, __shfl_xor(m, off, 64));
        float se = 0.f;
#pragma unroll
        for (int ct = 0; ct < CT; ct++) { v[ct] = __expf(v[ct] - m); se += v[ct]; }
#pragma unroll
        for (int off = 1; off <= 8; off <<= 1) se += __shfl_xor(se, off, 64);
        float inv = 1.0f / se;
#pragma unroll
        for (int ct = 0; ct < CT; ct++) v[ct] *= inv;
        float m2 = v[0];
#pragma unroll
        for (int ct = 1; ct < CT; ct++) m2 = fmaxf(m2, v[ct]);
#pragma unroll
        for (int off = 1; off <= 8; off <<= 1) m2 = fmaxf(m2, __shfl_xor(m2, off, 64));
        float se2 = 0.f;
#pragma unroll
        for (int ct = 0; ct < CT; ct++) { v[ct] = __expf(v[ct] - m2); se2 += v[ct]; }
#pragma unroll
        for (int off = 1; off <= 8; off <<= 1) se2 += __shfl_xor(se2, off, 64);
        float inv2 = 1.0f / se2;
        float qq = 0.f;
#pragma unroll
        for (int ct = 0; ct < CT; ct++) { v[ct] *= inv2; qq += v[ct] * v[ct]; }
#pragma unroll
        for (int off = 1; off <= 8; off <<= 1) qq += __shfl_xor(qq, off, 64);
        if (l16 == 0) dnp[row] = qq * (float)outdeg[row];
        _Float16* sh = (_Float16*)Cout;
#pragma unroll
        for (int ct = 0; ct < CT; ct++) sh[row * BN + ct * 16 + l16] = (_Float16)v[ct];
      } else {
        float sc = SCALE ? rowscale[row] : 1.f;
#pragma unroll
        for (int ct = 0; ct < CT; ct++) {
          float v = acc[rt][ct][r];
          if (SCALE) v *= sc;
          if (BIAS) v += bias[ct * 16 + l16];
          if (ACT == 1) v = fmaxf(v, 0.f);
          if (ACT == 2) v = tanhf(v);
          if (OUTH) ((_Float16*)Cout)[row * BN + ct * 16 + l16] = (_Float16)v;
          else ((float*)Cout)[row * BN + ct * 16 + l16] = v;
        }
      }
    }
  }
}

// ---------------- fp32 GEMM (final small one): C[M x 128] = A @ Wo + bias, relu ----------------
__global__ __launch_bounds__(256) void gemm_kernel(const float* __restrict__ A, const float* __restrict__ W,
                                                   const float* __restrict__ bias, float* __restrict__ C) {
  __shared__ float As[32][68];
  __shared__ float Ws[32][128];
  const int t = threadIdx.x;
  const int tn = t % 32;
  const int tm = t / 32;
  const long rowbase = (long)blockIdx.x * 64;
  float acc[8][4];
#pragma unroll
  for (int i = 0; i < 8; i++)
#pragma unroll
    for (int j = 0; j < 4; j++) acc[i][j] = 0.f;
  for (int k0 = 0; k0 < 128; k0 += 32) {
#pragma unroll
    for (int it = 0; it < 2; it++) {
      int lin = t + it * 256;
      int row = lin >> 3, c4 = lin & 7;
      float4 v = *reinterpret_cast<const float4*>(A + (rowbase + row) * 128 + k0 + c4 * 4);
      As[c4 * 4 + 0][row] = v.x;
      As[c4 * 4 + 1][row] = v.y;
      As[c4 * 4 + 2][row] = v.z;
      As[c4 * 4 + 3][row] = v.w;
    }
#pragma unroll
    for (int it = 0; it < 4; it++) {
      int lin = t + it * 256;
      int row = lin / 32, c4 = lin % 32;
      *reinterpret_cast<float4*>(&Ws[row][c4 * 4]) =
          *reinterpret_cast<const float4*>(W + (size_t)(k0 + row) * 128 + c4 * 4);
    }
    __syncthreads();
#pragma unroll
    for (int k = 0; k < 32; k++) {
      float4 wv = *reinterpret_cast<const float4*>(&Ws[k][tn * 4]);
      float a[8];
#pragma unroll
      for (int i = 0; i < 8; i += 4) {
        float4 av = *reinterpret_cast<const float4*>(&As[k][tm * 8 + i]);
        a[i] = av.x; a[i + 1] = av.y; a[i + 2] = av.z; a[i + 3] = av.w;
      }
#pragma unroll
      for (int i = 0; i < 8; i++) {
        acc[i][0] = fmaf(a[i], wv.x, acc[i][0]);
        acc[i][1] = fmaf(a[i], wv.y, acc[i][1]);
        acc[i][2] = fmaf(a[i], wv.z, acc[i][2]);
        acc[i][3] = fmaf(a[i], wv.w, acc[i][3]);
      }
    }
    __syncthreads();
  }
  float4 bv = *reinterpret_cast<const float4*>(bias + tn * 4);
#pragma unroll
  for (int i = 0; i < 8; i++) {
    float r0 = fmaxf(acc[i][0] + bv.x, 0.f);
    float r1 = fmaxf(acc[i][1] + bv.y, 0.f);
    float r2 = fmaxf(acc[i][2] + bv.z, 0.f);
    float r3 = fmaxf(acc[i][3] + bv.w, 0.f);
    float4 out4 = {r0, r1, r2, r3};
    *reinterpret_cast<float4*>(C + (rowbase + tm * 8 + i) * 128 + tn * 4) = out4;
  }
}

// ---------------- GCN aggregation over fp16 pre-scaled hs (XCD-swizzled) ----------------
__global__ __launch_bounds__(256) void aggregate_kernel(const _Float16* __restrict__ hs, const float* __restrict__ dis,
                                                        const int* __restrict__ offs, const int* __restrict__ ssrc,
                                                        const float* __restrict__ bias, _Float16* __restrict__ outh,
                                                        int relu) {
  const int lane = threadIdx.x & 63;
  const int b = blockIdx.x;
  const int node = ((b & 7) << 12) + ((b >> 3) << 2) + (threadIdx.x >> 6);
  const int q = lane >> 4;
  const int fl = (lane & 15) * 8;
  const int e0 = offs[node], e1 = offs[node + 1];
  float fa[8];
#pragma unroll
  for (int j = 0; j < 8; j++) fa[j] = 0.f;
  int e = e0;
  for (; e + 16 <= e1; e += 16) {
    int s0 = ssrc[e + q];
    int s1 = ssrc[e + 4 + q];
    int s2 = ssrc[e + 8 + q];
    int s3 = ssrc[e + 12 + q];
    half8v v0 = *reinterpret_cast<const half8v*>(hs + (size_t)s0 * 128 + fl);
    half8v v1 = *reinterpret_cast<const half8v*>(hs + (size_t)s1 * 128 + fl);
    half8v v2 = *reinterpret_cast<const half8v*>(hs + (size_t)s2 * 128 + fl);
    half8v v3 = *reinterpret_cast<const half8v*>(hs + (size_t)s3 * 128 + fl);
#pragma unroll
    for (int j = 0; j < 8; j++) fa[j] += (float)v0[j] + (float)v1[j] + (float)v2[j] + (float)v3[j];
  }
  for (; e < e1; e += 4) {
    int idx = e + q;
    bool valid = idx < e1;
    int s = valid ? ssrc[idx] : node;
    half8v v = *reinterpret_cast<const half8v*>(hs + (size_t)s * 128 + fl);
    if (valid) {
#pragma unroll
      for (int j = 0; j < 8; j++) fa[j] += (float)v[j];
    }
  }
#pragma unroll
  for (int j = 0; j < 8; j++) {
    fa[j] += __shfl_xor(fa[j], 16, 64);
    fa[j] += __shfl_xor(fa[j], 32, 64);
  }
  if (q == 0) {
    float dn = dis[node];
    half8v self = *reinterpret_cast<const half8v*>(hs + (size_t)node * 128 + fl);
    float4 b0 = *reinterpret_cast<const float4*>(bias + fl);
    float4 b1 = *reinterpret_cast<const float4*>(bias + fl + 4);
    float bb[8] = {b0.x, b0.y, b0.z, b0.w, b1.x, b1.y, b1.z, b1.w};
    half8v r;
#pragma unroll
    for (int j = 0; j < 8; j++) {
      float v = fmaf(fa[j] + (float)self[j], dn, bb[j]);
      if (relu) v = fmaxf(v, 0.f);
      r[j] = (_Float16)v;
    }
    *reinterpret_cast<half8v*>(outh + (size_t)node * 128 + fl) = r;
  }
}

// ---------------- G[m] = sum_{src->m} s_d[src]  (fp16 rows, 8 edges/wave, XCD-swizzled) ----------------
__global__ __launch_bounds__(256) void gather_kernel(const _Float16* __restrict__ sh, const int* __restrict__ offs,
                                                     const int* __restrict__ ssrc, _Float16* __restrict__ Gh) {
  const int lane = threadIdx.x & 63;
  const int b = blockIdx.x;
  const int node = ((b & 7) << 12) + ((b >> 3) << 2) + (threadIdx.x >> 6);
  const int q = lane >> 3;          // 0..7 edge slot
  const int fl = (lane & 7) * 8;    // 8 lanes x 8 halves = 64
  const int e0 = offs[node], e1 = offs[node + 1];
  float fa[8];
#pragma unroll
  for (int j = 0; j < 8; j++) fa[j] = 0.f;
  int e = e0;
  for (; e + 16 <= e1; e += 16) {
    int s0 = ssrc[e + q];
    int s1 = ssrc[e + 8 + q];
    half8v v0 = *reinterpret_cast<const half8v*>(sh + (size_t)s0 * 64 + fl);
    half8v v1 = *reinterpret_cast<const half8v*>(sh + (size_t)s1 * 64 + fl);
#pragma unroll
    for (int j = 0; j < 8; j++) fa[j] += (float)v0[j] + (float)v1[j];
  }
  for (; e < e1; e += 8) {
    int idx = e + q;
    bool valid = idx < e1;
    int s = valid ? ssrc[idx] : node;
    half8v v = *reinterpret_cast<const half8v*>(sh + (size_t)s * 64 + fl);
    if (valid) {
#pragma unroll
      for (int j = 0; j < 8; j++) fa[j] += (float)v[j];
    }
  }
#pragma unroll
  for (int j = 0; j < 8; j++) {
    fa[j] += __shfl_xor(fa[j], 8, 64);
    fa[j] += __shfl_xor(fa[j], 16, 64);
    fa[j] += __shfl_xor(fa[j], 32, 64);
  }
  if (q == 0) {
    half8v r;
#pragma unroll
    for (int j = 0; j < 8; j++) r[j] = (_Float16)fa[j];
    *reinterpret_cast<half8v*>(Gh + (size_t)node * 64 + fl) = r;
  }
}

// ---------------- fused rank reduction: C[64 x 256] = s_chunk^T [G | s | h2] ----------------
__global__ __launch_bounds__(512) void fused_atb_kernel(const _Float16* __restrict__ sh, const _Float16* __restrict__ Gh,
                                                        const _Float16* __restrict__ h2, float* __restrict__ pF) {
  __shared__ float Xs[32][64];
  __shared__ float Ys[32][256];
  const int t = threadIdx.x;
  const int g = blockIdx.x & 7, chunk = blockIdx.x >> 3;
  const int n0 = g * 4096 + chunk * 128;
  const int rg = t >> 6;
  const int cl = t & 63;
  float acc[8][4];
#pragma unroll
  for (int r = 0; r < 8; r++)
#pragma unroll
    for (int j = 0; j < 4; j++) acc[r][j] = 0.f;

  for (int kt = 0; kt < 4; ++kt) {
    const int nb = n0 + kt * 32;
    {
      int k = t >> 4, c = (t & 15) * 4;
      half4v hv = *reinterpret_cast<const half4v*>(&sh[(size_t)(nb + k) * 64 + c]);
      float4 val = {(float)hv[0], (float)hv[1], (float)hv[2], (float)hv[3]};
      *reinterpret_cast<float4*>(&Xs[k][c]) = val;
    }
#pragma unroll
    for (int it = 0; it < 4; ++it) {
      int slot = it * 512 + t;
      int k = slot >> 6, c = (slot & 63) * 4;
      half4v hv;
      if (c < 64)       hv = *reinterpret_cast<const half4v*>(&Gh[(size_t)(nb + k) * 64 + c]);
      else if (c < 128) hv = *reinterpret_cast<const half4v*>(&sh[(size_t)(nb + k) * 64 + (c - 64)]);
      else              hv = *reinterpret_cast<const half4v*>(&h2[(size_t)(nb + k) * 128 + (c - 128)]);
      float4 val = {(float)hv[0], (float)hv[1], (float)hv[2], (float)hv[3]};
      *reinterpret_cast<float4*>(&Ys[k][c]) = val;
    }
    __syncthreads();
#pragma unroll
    for (int k = 0; k < 32; ++k) {
      float4 b4 = *reinterpret_cast<const float4*>(&Ys[k][cl * 4]);
      float4 a0 = *reinterpret_cast<const float4*>(&Xs[k][rg * 8]);
      float4 a1 = *reinterpret_cast<const float4*>(&Xs[k][rg * 8 + 4]);
      float a[8] = {a0.x, a0.y, a0.z, a0.w, a1.x, a1.y, a1.z, a1.w};
#pragma unroll
      for (int r = 0; r < 8; r++) {
        acc[r][0] = fmaf(a[r], b4.x, acc[r][0]);
        acc[r][1] = fmaf(a[r], b4.y, acc[r][1]);
        acc[r][2] = fmaf(a[r], b4.z, acc[r][2]);
        acc[r][3] = fmaf(a[r], b4.w, acc[r][3]);
      }
    }
    __syncthreads();
  }
  float* dst = pF + (size_t)blockIdx.x * 16384;
#pragma unroll
  for (int r = 0; r < 8; r++) {
    float4 o4 = {acc[r][0], acc[r][1], acc[r][2], acc[r][3]};
    *reinterpret_cast<float4*>(&dst[(rg * 8 + r) * 256 + cl * 4]) = o4;
  }
}

// ---------------- merge 32 partials/graph -> oadj, ssb, outp ----------------
__global__ __launch_bounds__(256) void merge_kernel(const float* __restrict__ pF, float* __restrict__ oadj,
                                                    float* __restrict__ ssb, float* __restrict__ outp) {
  int idx = blockIdx.x * 256 + threadIdx.x;
  int g = idx >> 12, o4 = idx & 4095;
  float sx = 0.f, sy = 0.f, sz = 0.f, sw = 0.f;
#pragma unroll
  for (int q = 0; q < 32; ++q) {
    float4 v = *reinterpret_cast<const float4*>(pF + (size_t)(q * 8 + g) * 16384 + o4 * 4);
    sx += v.x; sy += v.y; sz += v.z; sw += v.w;
  }
  int row = o4 >> 6;
  int c = (o4 & 63) * 4;
  float4 o = {sx, sy, sz, sw};
  if (c < 64)
    *reinterpret_cast<float4*>(&oadj[g * 4096 + row * 64 + c]) = o;
  else if (c < 128)
    *reinterpret_cast<float4*>(&ssb[g * 4096 + row * 64 + (c - 64)]) = o;
  else
    *reinterpret_cast<float4*>(&outp[g * 8192 + row * 128 + (c - 128)]) = o;
}

// ---------------- losses + adjacency normalization + pooled_batch ----------------
__global__ __launch_bounds__(256) void epilogue_kernel(const float* __restrict__ oadj, const float* __restrict__ ssb,
                                                       const float* __restrict__ dn, float* __restrict__ out) {
  const int b = blockIdx.x, t = threadIdx.x;
  const float* A = oadj + b * 4096;
  const float* S = ssb + b * 4096;
  float da = 0.f;
#pragma unroll
  for (int i = 0; i < 16; i++) da += dn[b * 4096 + i * 256 + t];
  float dws = wave_sum(da);
  __shared__ float dw[4];
  if ((t & 63) == 0) dw[t >> 6] = dws;

  const int row = t >> 2, p = t & 3;
  float rs = 0.f, tra = 0.f, trs = 0.f, ssq = 0.f;
#pragma unroll
  for (int c = 0; c < 16; c++) {
    int j = p * 16 + c;
    float v = A[row * 64 + j];
    float w = S[row * 64 + j];
    ssq += w * w;
    if (j == row) { tra += v; trs += w; }
    else rs += v;
  }
  __shared__ float red[256];
  __shared__ float rowsum[64];
  red[t] = rs;
  __syncthreads();
  if (p == 0) rowsum[row] = red[t] + red[t + 1] + red[t + 2] + red[t + 3];
  float v1 = wave_sum(tra), v2 = wave_sum(trs), v3 = wave_sum(ssq);
  __shared__ float w1[4], w2[4], w3[4];
  if ((t & 63) == 0) { int w = t >> 6; w1[w] = v1; w2[w] = v2; w3[w] = v3; }
  __syncthreads();
  if (t == 0) {
    float TRA = w1[0] + w1[1] + w1[2] + w1[3];
    float TRS = w2[0] + w2[1] + w2[2] + w2[3];
    float SSQ = w3[0] + w3[1] + w3[2] + w3[3];
    float DEN = dw[0] + dw[1] + dw[2] + dw[3];
    atomicAdd(&out[98816], -(TRA / DEN) * 0.125f);
    float ssn = sqrtf(SSQ);
    atomicAdd(&out[98817], sqrtf(2.0f - TRS / (4.0f * ssn)) * 0.125f);
  }
  float di = sqrtf(rowsum[row]) + 1e-15f;
#pragma unroll
  for (int c = 0; c < 16; c++) {
    int j = p * 16 + c;
    float v = (j == row) ? 0.f : A[row * 64 + j];
    float dj = sqrtf(rowsum[j]) + 1e-15f;
    out[65536 + b * 4096 + row * 64 + j] = v / (di * dj);
  }
  if (t < 64) out[98304 + b * 64 + t] = (float)b;
}

extern "C" void kernel_launch(void* const* d_in, const int* in_sizes, int n_in,
                              void* d_out, int out_size, void* d_ws, size_t ws_size,
                              hipStream_t stream) {
  const float* x   = (const float*)d_in[0];
  const int*   ei  = (const int*)d_in[1];
  const float* W1  = (const float*)d_in[3];
  const float* b1  = (const float*)d_in[4];
  const float* W2  = (const float*)d_in[5];
  const float* b2  = (const float*)d_in[6];
  const float* Wa1 = (const float*)d_in[7];
  const float* ba1 = (const float*)d_in[8];
  const float* Wa2 = (const float*)d_in[9];
  const float* ba2 = (const float*)d_in[10];
  const float* Wo  = (const float*)d_in[11];
  const float* bo  = (const float*)d_in[12];
  const int* src = ei;
  const int* dst = ei + NEDGES;
  float* out = (float*)d_out;

  char* ws = (char*)d_ws;
  size_t o = 0;
  auto alloc = [&](size_t bytes) -> void* {
    void* p = ws + o;
    o += (bytes + 255) & ~(size_t)255;
    return p;
  };
  _Float16* h16A = (_Float16*)alloc((size_t)NNODES * 128 * 2);  // 8 MB
  _Float16* h16B = (_Float16*)alloc((size_t)NNODES * 128 * 2);  // 8 MB
  _Float16* h16C = (_Float16*)alloc((size_t)NNODES * 128 * 2);  // 8 MB (h2, persists)
  _Float16* sh   = (_Float16*)alloc((size_t)NNODES * 64 * 2);   // 4 MB (s_d fp16)
  _Float16* Gh   = (_Float16*)alloc((size_t)NNODES * 64 * 2);   // 4 MB
  float* pF    = (float*)alloc((size_t)256 * 16384 * 4);        // 16 MB
  float* dis   = (float*)alloc((size_t)NNODES * 4);
  int* outdeg  = (int*)alloc((size_t)NNODES * 4);
  int* offs    = (int*)alloc((size_t)(NNODES + 1) * 4);
  int* ssrc    = (int*)alloc((size_t)NEDGES * 4);
  int* pIn     = (int*)alloc((size_t)8 * CPG * 4096 * 4);
  int* pOut    = (int*)alloc((size_t)8 * CPG * 4096 * 4);
  int* cbase   = (int*)alloc((size_t)8 * CPG * 4096 * 4);
  float* dn    = (float*)alloc((size_t)NNODES * 4);
  float* oadj  = (float*)alloc(8 * 4096 * 4);
  float* ssb   = (float*)alloc(8 * 4096 * 4);
  float* outp  = (float*)alloc(8 * 8192 * 4);

  hipMemsetAsync(out + 98816, 0, 2 * sizeof(float), stream);

  hist2_kernel<<<8 * CPG, 256, 0, stream>>>(src, dst, pIn, pOut);
  scan2_kernel<<<8, 1024, 0, stream>>>(pIn, pOut, offs, cbase, outdeg, dis);
  scatter2_kernel<<<8 * CPG, 256, 0, stream>>>(src, dst, cbase, ssrc);

  // GCN layer 1: hs = dis .* (x @ W1) [fp32 in, fp16 out]; h1 = relu(...)
  mgemm_kernel<128, 0, 0, 1, 1, 1, 0><<<NNODES / 128, 256, 0, stream>>>(x, W1, nullptr, dis, nullptr, nullptr, h16A);
  aggregate_kernel<<<NNODES / 4, 256, 0, stream>>>(h16A, dis, offs, ssrc, b1, h16B, 1);
  // GCN layer 2: h2 [fp16]
  mgemm_kernel<128, 0, 0, 1, 0, 1, 0><<<NNODES / 128, 256, 0, stream>>>(h16B, W2, nullptr, dis, nullptr, nullptr, h16A);
  aggregate_kernel<<<NNODES / 4, 256, 0, stream>>>(h16A, dis, offs, ssrc, b2, h16C, 0);

  // assignment MLP: z = tanh(h2 @ Wa1 + ba1) [fp16]; s_d = dsoftmax(z @ Wa2 + ba2) [fp16, fused]
  mgemm_kernel<128, 2, 1, 0, 0, 1, 0><<<NNODES / 128, 256, 0, stream>>>(h16C, Wa1, ba1, nullptr, nullptr, nullptr, h16A);
  mgemm_kernel<64, 0, 1, 0, 0, 0, 1><<<NNODES / 128, 256, 0, stream>>>(h16A, Wa2, ba2, nullptr, outdeg, dn, sh);

  gather_kernel<<<NNODES / 4, 256, 0, stream>>>(sh, offs, ssrc, Gh);
  fused_atb_kernel<<<256, 512, 0, stream>>>(sh, Gh, h16C, pF);
  merge_kernel<<<128, 256, 0, stream>>>(pF, oadj, ssb, outp);

  gemm_kernel<<<8, 256, 0, stream>>>(outp, Wo, bo, out);
  epilogue_kernel<<<8, 256, 0, stream>>>(oadj, ssb, dn, out);
}